// Round 10
// baseline (209.672 us; speedup 1.0000x reference)
//
#include <hip/hip_runtime.h>
#include <hip/hip_bf16.h>

typedef __hip_bfloat16 bf16;
typedef _Float16 h16;
typedef __attribute__((ext_vector_type(8))) _Float16 h16x8;
typedef __attribute__((ext_vector_type(4))) float f32x4;
typedef __attribute__((ext_vector_type(16))) float f32x16;

__device__ __forceinline__ float lrelu(float x) { return fmaxf(x, 0.1f * x); }
__device__ __forceinline__ float ldE(const void* p, long i, int f32) {
    return f32 ? ((const float*)p)[i] : __bfloat162float(((const bf16*)p)[i]);
}
__device__ __forceinline__ uint2 pack4(float a, float b, float c, float d) {
    union { _Float16 h[4]; uint2 u; } t;
    t.h[0] = (_Float16)a; t.h[1] = (_Float16)b; t.h[2] = (_Float16)c; t.h[3] = (_Float16)d;
    return t.u;
}
__device__ __forceinline__ unsigned umx(unsigned a, unsigned b) { return a > b ? a : b; }
// Compiler-only ordering barrier: wave-private buffers + in-order DS pipe
// make s_waitcnt drains unnecessary (validated round 9: correct output).
#define LDS_FENCE() asm volatile("" ::: "memory")

// ---------------- workspace layout ----------------
// float region (wsf):
//   [64..79] fb1 [80..95] fb2 [96..127] fb3 [128..159] fb4
//   [160..223] fbd [224..287] qwo [288] fbo   int flag @ index 290
// f16 frag region wh = (h16*)(wsf+292):
//   F2 @0 (1024), F3 @1024 (2560), F4 @3584 (5120), FD @8704 (55296),
//   F1 @64000 (512)

__device__ __forceinline__ float qv(const void* src, int idx, float sc, int f32) {
    float w = ldE(src, idx, f32);
    float q = rintf(w / sc);                    // round-half-even like jnp.round
    return fminf(127.f, fmaxf(-127.f, q)) * sc; // clip then dequant
}

__device__ float block_scale(const void* src, int n, int f32, int tid, float* red) {
    unsigned m = 0;
    const uint4* p = (const uint4*)src;
    if (f32) {
        int nv = n >> 2;
        for (int i = tid; i < nv; i += 256) {
            uint4 u = p[i];
            m = umx(m, u.x & 0x7FFFFFFFu); m = umx(m, u.y & 0x7FFFFFFFu);
            m = umx(m, u.z & 0x7FFFFFFFu); m = umx(m, u.w & 0x7FFFFFFFu);
        }
        union { unsigned u; float f; } c; c.u = m;
        red[tid] = c.f;
    } else {
        int nv = n >> 3;
        for (int i = tid; i < nv; i += 256) {
            uint4 u = p[i];
            unsigned a;
            a = u.x & 0x7FFF7FFFu; m = umx(m, a >> 16); m = umx(m, a & 0xFFFFu);
            a = u.y & 0x7FFF7FFFu; m = umx(m, a >> 16); m = umx(m, a & 0xFFFFu);
            a = u.z & 0x7FFF7FFFu; m = umx(m, a >> 16); m = umx(m, a & 0xFFFFu);
            a = u.w & 0x7FFF7FFFu; m = umx(m, a >> 16); m = umx(m, a & 0xFFFFu);
        }
        union { unsigned u; float f; } c; c.u = m << 16;
        red[tid] = c.f;
    }
    __syncthreads();
    for (int s = 128; s > 0; s >>= 1) {
        if (tid < s) red[tid] = fmaxf(red[tid], red[tid + s]);
        __syncthreads();
    }
    return red[0] / 127.f;
}

// grid = 57: 0..47 FD slices, 48 F1, 49 F2, 50..51 F3, 52..55 F4,
// 56 qwo + biases + dtype flag.
__global__ void __launch_bounds__(256) prep(
    const unsigned short* __restrict__ xu,
    const void* __restrict__ w1, const void* __restrict__ w2,
    const void* __restrict__ w3, const void* __restrict__ w4,
    const void* __restrict__ wd, const void* __restrict__ wo,
    const void* __restrict__ b1, const void* __restrict__ b2,
    const void* __restrict__ b3, const void* __restrict__ b4,
    const void* __restrict__ bd, const void* __restrict__ bo,
    float* __restrict__ wsf)
{
    int tid = threadIdx.x, which = blockIdx.x;
    __shared__ float red[256];
    __shared__ int cnt;
    if (tid == 0) cnt = 0;
    __syncthreads();
    int bad = 0;
    for (int i = tid; i < 2048; i += 256) {
        int e = (xu[i] >> 7) & 0xFF;
        if (e >= 147) bad = 1;            // |v| >= 2^20: x is not bf16 data
    }
    atomicAdd(&cnt, bad);
    __syncthreads();
    const int f32 = (cnt > 4) ? 1 : 0;
    h16* wh = (h16*)(wsf + 292);

    if (which < 48) {
        float sc = block_scale(wd, 55296, f32, tid, red);
        int e1 = (which + 1) * 1152;
        for (int e = which * 1152 + tid; e < e1; e += 256) {
            int j = e & 7, l = (e >> 3) & 63, t = e >> 9;   // t = mt*27 + c
            int mt = t / 27, c = t - mt * 27;
            int o = mt * 16 + (l & 15);
            int k = c * 32 + ((l >> 4) & 3) * 8 + j;
            int i = k >> 5, cch = k & 31;
            wh[8704 + e] = (h16)qv(wd, o * 864 + cch * 27 + i, sc, f32);
        }
    } else if (which == 48) {
        float sc = block_scale(w1, 64, f32, tid, red);
        for (int e = tid; e < 512; e += 256) {
            int l = e >> 3, j = e & 7;
            int co = l & 15, kg = (l >> 4) & 3;
            float v = (kg < 2 && j < 2) ? qv(w1, co * 4 + j * 2 + kg, sc, f32) : 0.f;
            wh[64000 + e] = (h16)v;
        }
    } else if (which == 49) {
        float sc = block_scale(w2, 768, f32, tid, red);
        for (int e = tid; e < 1024; e += 256) {
            int c = e >> 9, l = (e >> 3) & 63, j = e & 7;
            int mm = l & 15;
            int k = c * 32 + ((l >> 4) & 3) * 8 + j;
            int dk = k >> 4, ci = k & 15;
            float v = (dk < 3) ? qv(w2, (mm * 16 + ci) * 3 + dk, sc, f32) : 0.f;
            wh[0 + e] = (h16)v;
        }
    } else if (which < 52) {
        float sc = block_scale(w3, 2560, f32, tid, red);
        int e0 = (which - 50) * 1280;
        for (int e = e0 + tid; e < e0 + 1280; e += 256) {
            int c = e >> 9, l = (e >> 3) & 63, j = e & 7;
            int mm = l & 31;
            int ci = ((l >> 5) & 1) * 8 + j;
            wh[1024 + e] = (h16)qv(w3, (mm * 16 + ci) * 5 + c, sc, f32);
        }
    } else if (which < 56) {
        float sc = block_scale(w4, 5120, f32, tid, red);
        int e0 = (which - 52) * 1280;
        for (int e = e0 + tid; e < e0 + 1280; e += 256) {
            int c = e >> 9, l = (e >> 3) & 63, j = e & 7;
            int mm = l & 31;
            int k = c * 16 + ((l >> 5) & 1) * 8 + j;
            int dk = k >> 5, ci = k & 31;
            wh[3584 + e] = (h16)qv(w4, (mm * 32 + ci) * 5 + dk, sc, f32);
        }
    } else {
        float sc = block_scale(wo, 64, f32, tid, red);
        if (tid < 64) wsf[224 + tid] = qv(wo, tid, sc, f32);
        if (tid < 16)        wsf[64 + tid]        = ldE(b1, tid, f32);
        else if (tid < 32)   wsf[80 + tid - 16]   = ldE(b2, tid - 16, f32);
        else if (tid < 64)   wsf[96 + tid - 32]   = ldE(b3, tid - 32, f32);
        else if (tid < 96)   wsf[128 + tid - 64]  = ldE(b4, tid - 64, f32);
        else if (tid < 160)  wsf[160 + tid - 96]  = ldE(bd, tid - 96, f32);
        else if (tid == 160) wsf[288]             = ldE(bo, 0, f32);
        if (tid == 0) ((int*)wsf)[290] = f32;
    }
}

// 128-thread blocks (2 waves, 4 samples): LDS 24.5KB -> 6 blocks/CU (2x the
// resident waves of the 256-thread/49.6KB config — attack the TLP-starved
// latency-bound regime). Pool-interleaved physical rows for act2/act4: conv
// epilogues write even positions to rows 0.., odd to rows 64../32.., so pool
// reads are stride-1 b128 (kills the 4-way stride-2 conflicts). Dense is done
// per-block over its 4 samples (cols n16&3): 2 mt per wave, modest MFMA
// redundancy in exchange for no flatb[8] and barrier-free conv stack.
__global__ void __launch_bounds__(128, 4) qcnn_main(
    const void* __restrict__ x,      // [B][2][128] bf16 or f32
    const float* __restrict__ wsf,
    void* __restrict__ out)          // [B]
{
    const int f32flag = ((const int*)wsf)[290];
    const h16*  wh  = (const h16*)(wsf + 292);
    const h16*  F2g = wh;
    const h16*  F3g = wh + 1024;
    const h16*  F4g = wh + 3584;
    const h16*  FDg = wh + 8704;
    const h16*  F1g = wh + 64000;

    __shared__ __align__(16) h16 Uall[2][2112];   // act1 2gx132 / pooled / act4 4gx64
    __shared__ __align__(16) h16 Vall[2][2208];   // xi8 / act2 2gx126 / act3 4gx69
    __shared__ __align__(16) h16 flatb[4][872];
    __shared__ float red[64];

    int tid  = threadIdx.x;
    int lane = tid & 63;
    int w    = __builtin_amdgcn_readfirstlane(tid >> 6);   // 0..1
    int n16  = lane & 15, kg16 = (lane >> 4) & 3;
    int n32  = lane & 31, kg32 = (lane >> 5) & 1;
    int o16  = kg16 * 4;
    h16* U = Uall[w];
    h16* V = Vall[w];
    long b0 = (long)blockIdx.x * 4;

    // loop-invariant A fragments (16B/lane coalesced)
    h16x8 a1, a2[2], a3[5], a4[10];
    a1 = *(const h16x8*)&F1g[lane * 8];
#pragma unroll
    for (int c = 0; c < 2; ++c)  a2[c] = *(const h16x8*)&F2g[c * 512 + lane * 8];
#pragma unroll
    for (int c = 0; c < 5; ++c)  a3[c] = *(const h16x8*)&F3g[c * 512 + lane * 8];
#pragma unroll
    for (int c = 0; c < 10; ++c) a4[c] = *(const h16x8*)&F4g[c * 512 + lane * 8];
    f32x4 b1v = *(const f32x4*)&wsf[64 + o16];   // conv1 C-init
    f32x4 b2v = *(const f32x4*)&wsf[80 + o16];   // conv2 C-init

    const h16 hz = (h16)0.f;
    const h16x8 zrow = {hz, hz, hz, hz, hz, hz, hz, hz};

    for (int it = 0; it < 2; ++it) {
        int slot = w * 2 + it;                  // 0..3
        long sb = (b0 + slot) * 256;

        // ---- stage x as xi8 rows in V ----
        LDS_FENCE();
        {
            float x00 = ldE(x, sb + lane, f32flag);
            float x10 = ldE(x, sb + 128 + lane, f32flag);
            float x01 = ldE(x, sb + 64 + lane, f32flag);
            float x11 = ldE(x, sb + 192 + lane, f32flag);
            h16x8 r0 = zrow, r1 = zrow;
            r0[0] = (h16)x00; r0[1] = (h16)x10;
            r1[0] = (h16)x01; r1[1] = (h16)x11;
            *(h16x8*)&V[lane * 8]        = r0;
            *(h16x8*)&V[(64 + lane) * 8] = r1;
            if (lane < 3) *(h16x8*)&V[(128 + lane) * 8] = zrow;
        }
        LDS_FENCE();

        // ---- conv1 (16x16x32): xi8 -> act1 U[2g][127] (linear rows) ----
#pragma unroll
        for (int t = 0; t < 8; ++t) {
            int n = t * 16 + n16;
            f32x4 acc = b1v;
            h16x8 bfr = *(const h16x8*)&V[(n + kg16) * 8];
            acc = __builtin_amdgcn_mfma_f32_16x16x32_f16(a1, bfr, acc, 0, 0, 0);
            if (n < 127) {
                uint2 p = pack4(lrelu(acc[0]), lrelu(acc[1]), lrelu(acc[2]), lrelu(acc[3]));
                *(uint2*)&U[(o16 >> 3) * 1056 + n * 8 + (o16 & 7)] = p;
            }
        }
        if (lane < 8) {   // zero act1 pad rows 127..130
            int g = lane & 1, row = 127 + (lane >> 1);
            *(uint4*)&U[g * 1056 + row * 8] = make_uint4(0, 0, 0, 0);
        }
        LDS_FENCE();

        // ---- conv2: act1 -> act2 V[2g][126], POOL-INTERLEAVED rows:
        //      phys = (n&1)*64 + (n>>1)  (even pos -> 0..62, odd -> 64..125)
#pragma unroll
        for (int t = 0; t < 8; ++t) {
            int n = t * 16 + n16;
            f32x4 acc = b2v;
#pragma unroll
            for (int c = 0; c < 2; ++c) {
                int k0 = c * 32 + kg16 * 8;
                int dk = k0 >> 4, g = (k0 & 15) >> 3;
                h16x8 bfr = *(const h16x8*)&U[g * 1056 + (n + dk) * 8];
                acc = __builtin_amdgcn_mfma_f32_16x16x32_f16(a2[c], bfr, acc, 0, 0, 0);
            }
            if (n < 125) {
                int ph = (n & 1) * 64 + (n >> 1);
                uint2 p = pack4(lrelu(acc[0]), lrelu(acc[1]), lrelu(acc[2]), lrelu(acc[3]));
                *(uint2*)&V[(o16 >> 3) * 1008 + ph * 8 + (o16 & 7)] = p;
            }
        }
        LDS_FENCE();

        // ---- pool1 (stride-1 reads): act2 -> pooled U[2g][62] ----
        if (lane < 62) {
#pragma unroll
            for (int g = 0; g < 2; ++g) {
                h16x8 pa = *(const h16x8*)&V[g * 1008 + lane * 8];         // even pos
                h16x8 pb = *(const h16x8*)&V[g * 1008 + (64 + lane) * 8];  // odd pos
                h16x8 mm;
#pragma unroll
                for (int e = 0; e < 8; ++e) mm[e] = pa[e] > pb[e] ? pa[e] : pb[e];
                *(h16x8*)&U[g * 1056 + lane * 8] = mm;
            }
        }
        LDS_FENCE();

        // ---- conv3 (32x32x16): pooled -> act3 V[4g][69] (linear rows) ----
#pragma unroll
        for (int t = 0; t < 2; ++t) {
            int n = t * 32 + n32;
            f32x16 acc = {0.f,0.f,0.f,0.f,0.f,0.f,0.f,0.f,0.f,0.f,0.f,0.f,0.f,0.f,0.f,0.f};
#pragma unroll
            for (int c = 0; c < 5; ++c) {
                h16x8 bfr = *(const h16x8*)&U[kg32 * 1056 + (n + c) * 8];
                acc = __builtin_amdgcn_mfma_f32_32x32x16_f16(a3[c], bfr, acc, 0, 0, 0);
            }
            if (n < 58) {
#pragma unroll
                for (int g = 0; g < 4; ++g) {
                    int r0 = 8 * g + 4 * kg32;
                    f32x4 bv = *(const f32x4*)&wsf[96 + r0];
                    uint2 p = pack4(lrelu(acc[4*g+0] + bv[0]), lrelu(acc[4*g+1] + bv[1]),
                                    lrelu(acc[4*g+2] + bv[2]), lrelu(acc[4*g+3] + bv[3]));
                    *(uint2*)&V[g * 552 + n * 8 + 4 * kg32] = p;
                }
            }
        }
        LDS_FENCE();

        // ---- conv4: act3 -> act4 U[4g][64], POOL-INTERLEAVED:
        //      phys = (n&1)*32 + (n>>1)  (even -> 0..26, odd -> 32..58)
#pragma unroll
        for (int t = 0; t < 2; ++t) {
            int n = t * 32 + n32;
            f32x16 acc = {0.f,0.f,0.f,0.f,0.f,0.f,0.f,0.f,0.f,0.f,0.f,0.f,0.f,0.f,0.f,0.f};
#pragma unroll
            for (int c = 0; c < 10; ++c) {
                int k0 = c * 16 + kg32 * 8;
                int dk = k0 >> 5, g = (k0 >> 3) & 3;
                h16x8 bfr = *(const h16x8*)&V[g * 552 + (n + dk) * 8];
                acc = __builtin_amdgcn_mfma_f32_32x32x16_f16(a4[c], bfr, acc, 0, 0, 0);
            }
            if (n < 54) {
                int ph = (n & 1) * 32 + (n >> 1);
#pragma unroll
                for (int g = 0; g < 4; ++g) {
                    int r0 = 8 * g + 4 * kg32;
                    f32x4 bv = *(const f32x4*)&wsf[128 + r0];
                    uint2 p = pack4(lrelu(acc[4*g+0] + bv[0]), lrelu(acc[4*g+1] + bv[1]),
                                    lrelu(acc[4*g+2] + bv[2]), lrelu(acc[4*g+3] + bv[3]));
                    *(uint2*)&U[g * 512 + ph * 8 + 4 * kg32] = p;
                }
            }
        }
        LDS_FENCE();

        // ---- pool2 (stride-1 reads) + flatten: act4 -> flatb[slot] ----
        if (lane < 27) {
#pragma unroll
            for (int g = 0; g < 4; ++g) {
                h16x8 pa = *(const h16x8*)&U[g * 512 + lane * 8];          // even pos
                h16x8 pb = *(const h16x8*)&U[g * 512 + (32 + lane) * 8];   // odd pos
                h16x8 mm;
#pragma unroll
                for (int e = 0; e < 8; ++e) mm[e] = pa[e] > pb[e] ? pa[e] : pb[e];
                *(h16x8*)&flatb[slot][(g * 27 + lane) * 8] = mm;
            }
        }
    }
    __syncthreads();   // cross-wave: dense reads all 4 flatb slots

    // ---- dense (16x16x32): 4 samples in cols (n16&3), wave w does mt {2w,2w+1} ----
#pragma unroll
    for (int mtl = 0; mtl < 2; ++mtl) {
        int mt = w * 2 + mtl;
        f32x4 dacc = *(const f32x4*)&wsf[160 + mt * 16 + o16];  // bias in C
        for (int c = 0; c < 27; ++c) {
            h16x8 aw = *(const h16x8*)&FDg[((mt * 27 + c) * 64 + lane) * 8];
            h16x8 bh = *(const h16x8*)&flatb[lane & 3][(kg16 * 27 + c) * 8];
            dacc = __builtin_amdgcn_mfma_f32_16x16x32_f16(aw, bh, dacc, 0, 0, 0);
        }
        f32x4 qov = *(const f32x4*)&wsf[224 + mt * 16 + o16];
        float part = 0.f;
#pragma unroll
        for (int q = 0; q < 4; ++q) part += lrelu(dacc[q]) * qov[q];
        if (n16 < 4) red[n16 * 16 + w * 8 + mtl * 4 + kg16] = part;
    }
    __syncthreads();
    if (tid < 4) {
        float y = wsf[288];
#pragma unroll
        for (int j = 0; j < 16; ++j) y += red[tid * 16 + j];
        if (f32flag) ((float*)out)[b0 + tid] = y;
        else         ((bf16*)out)[b0 + tid] = __float2bfloat16(y);
    }
}

extern "C" void kernel_launch(void* const* d_in, const int* in_sizes, int n_in,
                              void* d_out, int out_size, void* d_ws, size_t ws_size,
                              hipStream_t stream) {
    const void* x  = d_in[0];
    const void* w1 = d_in[1];
    const void* b1 = d_in[2];
    const void* w2 = d_in[3];
    const void* b2 = d_in[4];
    const void* w3 = d_in[5];
    const void* b3 = d_in[6];
    const void* w4 = d_in[7];
    const void* b4 = d_in[8];
    const void* wd = d_in[9];
    const void* bd = d_in[10];
    const void* wo = d_in[11];
    const void* bo = d_in[12];
    float* wsf = (float*)d_ws;

    int B = in_sizes[0] / 256;            // 32768
    prep<<<57, 256, 0, stream>>>((const unsigned short*)x,
                                 w1, w2, w3, w4, wd, wo,
                                 b1, b2, b3, b4, bd, bo, wsf);
    qcnn_main<<<B / 4, 128, 0, stream>>>(x, wsf, d_out);
}

// Round 11
// 194.702 us; speedup vs baseline: 1.0769x; 1.0769x over previous
//
#include <hip/hip_runtime.h>
#include <hip/hip_bf16.h>

typedef __hip_bfloat16 bf16;
typedef _Float16 h16;
typedef __attribute__((ext_vector_type(8))) _Float16 h16x8;
typedef __attribute__((ext_vector_type(4))) float f32x4;
typedef __attribute__((ext_vector_type(16))) float f32x16;

__device__ __forceinline__ float lrelu(float x) { return fmaxf(x, 0.1f * x); }
__device__ __forceinline__ float ldE(const void* p, long i, int f32) {
    return f32 ? ((const float*)p)[i] : __bfloat162float(((const bf16*)p)[i]);
}
__device__ __forceinline__ uint2 pack4(float a, float b, float c, float d) {
    union { _Float16 h[4]; uint2 u; } t;
    t.h[0] = (_Float16)a; t.h[1] = (_Float16)b; t.h[2] = (_Float16)c; t.h[3] = (_Float16)d;
    return t.u;
}
__device__ __forceinline__ unsigned umx(unsigned a, unsigned b) { return a > b ? a : b; }
// Compiler-only ordering barrier: wave-private buffers + in-order DS pipe
// make s_waitcnt drains unnecessary (validated round 9: correct output).
#define LDS_FENCE() asm volatile("" ::: "memory")

// ---------------- workspace layout ----------------
// float region (wsf):
//   [64..79] fb1 [80..95] fb2 [96..127] fb3 [128..159] fb4
//   [160..223] fbd [224..287] qwo [288] fbo   int flag @ index 290
// f16 frag region wh = (h16*)(wsf+292):
//   F2 @0 (1024), F3 @1024 (2560), F4 @3584 (5120), FD @8704 (55296),
//   F1 @64000 (512)

__device__ __forceinline__ float qv(const void* src, int idx, float sc, int f32) {
    float w = ldE(src, idx, f32);
    float q = rintf(w / sc);                    // round-half-even like jnp.round
    return fminf(127.f, fmaxf(-127.f, q)) * sc; // clip then dequant
}

__device__ float block_scale(const void* src, int n, int f32, int tid, float* red) {
    unsigned m = 0;
    const uint4* p = (const uint4*)src;
    if (f32) {
        int nv = n >> 2;
        for (int i = tid; i < nv; i += 256) {
            uint4 u = p[i];
            m = umx(m, u.x & 0x7FFFFFFFu); m = umx(m, u.y & 0x7FFFFFFFu);
            m = umx(m, u.z & 0x7FFFFFFFu); m = umx(m, u.w & 0x7FFFFFFFu);
        }
        union { unsigned u; float f; } c; c.u = m;
        red[tid] = c.f;
    } else {
        int nv = n >> 3;
        for (int i = tid; i < nv; i += 256) {
            uint4 u = p[i];
            unsigned a;
            a = u.x & 0x7FFF7FFFu; m = umx(m, a >> 16); m = umx(m, a & 0xFFFFu);
            a = u.y & 0x7FFF7FFFu; m = umx(m, a >> 16); m = umx(m, a & 0xFFFFu);
            a = u.z & 0x7FFF7FFFu; m = umx(m, a >> 16); m = umx(m, a & 0xFFFFu);
            a = u.w & 0x7FFF7FFFu; m = umx(m, a >> 16); m = umx(m, a & 0xFFFFu);
        }
        union { unsigned u; float f; } c; c.u = m << 16;
        red[tid] = c.f;
    }
    __syncthreads();
    for (int s = 128; s > 0; s >>= 1) {
        if (tid < s) red[tid] = fmaxf(red[tid], red[tid + s]);
        __syncthreads();
    }
    float r = red[0] / 127.f;   // exact division, matches np max|w|/127
    __syncthreads();
    return r;
}

// Source-driven prep: coalesced LINEAR reads of each weight tensor, inverse-
// mapped scatter STORES into fragment order (stores don't stall; L2 write-
// combines). grid = 220: 0..215 FD (1 elem/thread), 216 F1+F2, 217 F3,
// 218 F4, 219 qwo+biases+flag. Every block derives the dtype flag and its
// tensor scale locally (coalesced scans, bit-identical across blocks).
__global__ void __launch_bounds__(256) prep(
    const unsigned short* __restrict__ xu,
    const void* __restrict__ w1, const void* __restrict__ w2,
    const void* __restrict__ w3, const void* __restrict__ w4,
    const void* __restrict__ wd, const void* __restrict__ wo,
    const void* __restrict__ b1, const void* __restrict__ b2,
    const void* __restrict__ b3, const void* __restrict__ b4,
    const void* __restrict__ bd, const void* __restrict__ bo,
    float* __restrict__ wsf)
{
    int tid = threadIdx.x, which = blockIdx.x;
    __shared__ float red[256];
    __shared__ int cnt;
    if (tid == 0) cnt = 0;
    __syncthreads();
    int bad = 0;
    for (int i = tid; i < 2048; i += 256) {
        int e = (xu[i] >> 7) & 0xFF;      // bf16 exponent of x's halfwords
        if (e >= 147) bad = 1;            // |v| >= 2^20: x is not bf16 data
    }
    atomicAdd(&cnt, bad);
    __syncthreads();
    const int f32 = (cnt > 4) ? 1 : 0;
    h16* wh = (h16*)(wsf + 292);

    if (which < 216) {
        // FD: source index s -> dest frag index e.
        // fwd mapping (r9): src = o*864 + cch*27 + i with o=mt*16+(l&15),
        // cch=kg*8+j, i=c;  e = ((mt*27+c)*64 + (l&15)+kg*16)*8 + j
        float sc = block_scale(wd, 55296, f32, tid, red);
        int s = which * 256 + tid;                 // 216*256 = 55296 exact
        int o = s / 864, r = s - o * 864;
        int cch = r / 27, i = r - cch * 27;
        int mt = o >> 4;
        int e = ((mt * 27 + i) * 64 + (o & 15) + (cch >> 3) * 16) * 8 + (cch & 7);
        wh[8704 + e] = (h16)qv(wd, s, sc, f32);
    } else if (which == 216) {
        // F1 (zero 512, fill 64) + F2 (zero 1024, fill 768)
        float s1 = block_scale(w1, 64, f32, tid, red);
        float s2 = block_scale(w2, 768, f32, tid, red);
        for (int e = tid; e < 512; e += 256)  wh[64000 + e] = (h16)0.f;
        for (int e = tid; e < 1024; e += 256) wh[e] = (h16)0.f;
        __syncthreads();
        if (tid < 64) {    // w1[co][ci][dk]: s = co*4 + ci*2 + dk
            int s = tid, co = s >> 2, ci = (s >> 1) & 1, dk = s & 1;
            wh[64000 + (co + dk * 16) * 8 + ci] = (h16)qv(w1, s, s1, f32);
        }
        for (int s = tid; s < 768; s += 256) {  // w2: s = (mm*16+ci)*3 + dk
            int mm = s / 48, r = s - mm * 48;
            int ci = r / 3, dk = r - ci * 3;
            int k = dk * 16 + ci;
            int e = (k >> 5) * 512 + (mm + ((k >> 3) & 3) * 16) * 8 + (k & 7);
            wh[e] = (h16)qv(w2, s, s2, f32);
        }
    } else if (which == 217) {
        // F3: w3 s = (mm*16+ci)*5 + dk; e = (dk*64 + mm + (ci>>3)*32)*8 + (ci&7)
        float sc = block_scale(w3, 2560, f32, tid, red);
        for (int s = tid; s < 2560; s += 256) {
            int mm = s / 80, r = s - mm * 80;
            int ci = r / 5, dk = r - ci * 5;
            int e = (dk * 64 + mm + (ci >> 3) * 32) * 8 + (ci & 7);
            wh[1024 + e] = (h16)qv(w3, s, sc, f32);
        }
    } else if (which == 218) {
        // F4: w4 s = (mm*32+ci)*5 + dk; k = dk*32+ci;
        //     e = (k>>4)*512 + (mm + ((k>>3)&1)*32)*8 + (k&7)
        float sc = block_scale(w4, 5120, f32, tid, red);
        for (int s = tid; s < 5120; s += 256) {
            int mm = s / 160, r = s - mm * 160;
            int ci = r / 5, dk = r - ci * 5;
            int k = dk * 32 + ci;
            int e = (k >> 4) * 512 + (mm + ((k >> 3) & 1) * 32) * 8 + (k & 7);
            wh[3584 + e] = (h16)qv(w4, s, sc, f32);
        }
    } else {
        float sc = block_scale(wo, 64, f32, tid, red);
        if (tid < 64) wsf[224 + tid] = qv(wo, tid, sc, f32);
        if (tid < 16)        wsf[64 + tid]        = ldE(b1, tid, f32);
        else if (tid < 32)   wsf[80 + tid - 16]   = ldE(b2, tid - 16, f32);
        else if (tid < 64)   wsf[96 + tid - 32]   = ldE(b3, tid - 32, f32);
        else if (tid < 96)   wsf[128 + tid - 64]  = ldE(b4, tid - 64, f32);
        else if (tid < 160)  wsf[160 + tid - 96]  = ldE(bd, tid - 96, f32);
        else if (tid == 160) wsf[288]             = ldE(bo, 0, f32);
        if (tid == 0) ((int*)wsf)[290] = f32;
    }
}

// r9 main (best measured: 112.7 µs): 256 threads, all convs on MFMA, chunked
// [k-group][pos][8 h16] LDS layouts, compiler-only stage fences.
__global__ void __launch_bounds__(256, 2) qcnn_main(
    const void* __restrict__ x,      // [B][2][128] bf16 or f32
    const float* __restrict__ wsf,
    void* __restrict__ out)          // [B]
{
    const int f32flag = ((const int*)wsf)[290];
    const h16*  wh  = (const h16*)(wsf + 292);
    const h16*  F2g = wh;
    const h16*  F3g = wh + 1024;
    const h16*  F4g = wh + 3584;
    const h16*  FDg = wh + 8704;
    const h16*  F1g = wh + 64000;

    __shared__ __align__(16) h16 Uall[4][2112];
    __shared__ __align__(16) h16 Vall[4][2208];
    __shared__ __align__(16) h16 flatb[8][872];
    __shared__ float red[256];

    int tid  = threadIdx.x;
    int lane = tid & 63;
    int w    = __builtin_amdgcn_readfirstlane(tid >> 6);
    int n16  = lane & 15, kg16 = (lane >> 4) & 3;
    int n32  = lane & 31, kg32 = (lane >> 5) & 1;
    int o16  = kg16 * 4;
    h16* U = Uall[w];
    h16* V = Vall[w];
    long b0 = (long)blockIdx.x * 8;

    h16x8 a1, a2[2], a3[5], a4[10];
    a1 = *(const h16x8*)&F1g[lane * 8];
#pragma unroll
    for (int c = 0; c < 2; ++c)  a2[c] = *(const h16x8*)&F2g[c * 512 + lane * 8];
#pragma unroll
    for (int c = 0; c < 5; ++c)  a3[c] = *(const h16x8*)&F3g[c * 512 + lane * 8];
#pragma unroll
    for (int c = 0; c < 10; ++c) a4[c] = *(const h16x8*)&F4g[c * 512 + lane * 8];
    f32x4 b1v = *(const f32x4*)&wsf[64 + o16];   // conv1 C-init
    f32x4 b2v = *(const f32x4*)&wsf[80 + o16];   // conv2 C-init

    const h16 hz = (h16)0.f;
    const h16x8 zrow = {hz, hz, hz, hz, hz, hz, hz, hz};

    for (int it = 0; it < 2; ++it) {
        int slot = w * 2 + it;
        long sb = (b0 + slot) * 256;

        // ---- stage x as xi8 rows in V ----
        LDS_FENCE();
        {
            float x00 = ldE(x, sb + lane, f32flag);
            float x10 = ldE(x, sb + 128 + lane, f32flag);
            float x01 = ldE(x, sb + 64 + lane, f32flag);
            float x11 = ldE(x, sb + 192 + lane, f32flag);
            h16x8 r0 = zrow, r1 = zrow;
            r0[0] = (h16)x00; r0[1] = (h16)x10;
            r1[0] = (h16)x01; r1[1] = (h16)x11;
            *(h16x8*)&V[lane * 8]        = r0;
            *(h16x8*)&V[(64 + lane) * 8] = r1;
            if (lane < 3) *(h16x8*)&V[(128 + lane) * 8] = zrow;
        }
        LDS_FENCE();

        // ---- conv1 (16x16x32): xi8 -> act1 U[2g][127] ----
#pragma unroll
        for (int t = 0; t < 8; ++t) {
            int n = t * 16 + n16;
            f32x4 acc = b1v;
            h16x8 bfr = *(const h16x8*)&V[(n + kg16) * 8];
            acc = __builtin_amdgcn_mfma_f32_16x16x32_f16(a1, bfr, acc, 0, 0, 0);
            if (n < 127) {
                uint2 p = pack4(lrelu(acc[0]), lrelu(acc[1]), lrelu(acc[2]), lrelu(acc[3]));
                *(uint2*)&U[(o16 >> 3) * 1056 + n * 8 + (o16 & 7)] = p;
            }
        }
        if (lane < 8) {   // zero act1 pad rows 127..130
            int g = lane & 1, row = 127 + (lane >> 1);
            *(uint4*)&U[g * 1056 + row * 8] = make_uint4(0, 0, 0, 0);
        }
        LDS_FENCE();

        // ---- conv2 (16x16x32): act1 -> act2 V[2g][125] ----
#pragma unroll
        for (int t = 0; t < 8; ++t) {
            int n = t * 16 + n16;
            f32x4 acc = b2v;
#pragma unroll
            for (int c = 0; c < 2; ++c) {
                int k0 = c * 32 + kg16 * 8;
                int dk = k0 >> 4, g = (k0 & 15) >> 3;
                h16x8 bfr = *(const h16x8*)&U[g * 1056 + (n + dk) * 8];
                acc = __builtin_amdgcn_mfma_f32_16x16x32_f16(a2[c], bfr, acc, 0, 0, 0);
            }
            if (n < 125) {
                uint2 p = pack4(lrelu(acc[0]), lrelu(acc[1]), lrelu(acc[2]), lrelu(acc[3]));
                *(uint2*)&V[(o16 >> 3) * 1008 + n * 8 + (o16 & 7)] = p;
            }
        }
        LDS_FENCE();

        // ---- pool1: act2 -> pooled U[2g][62] ----
        if (lane < 62) {
#pragma unroll
            for (int g = 0; g < 2; ++g) {
                h16x8 pa = *(const h16x8*)&V[g * 1008 + (2 * lane) * 8];
                h16x8 pb = *(const h16x8*)&V[g * 1008 + (2 * lane + 1) * 8];
                h16x8 mm;
#pragma unroll
                for (int e = 0; e < 8; ++e) mm[e] = pa[e] > pb[e] ? pa[e] : pb[e];
                *(h16x8*)&U[g * 1056 + lane * 8] = mm;
            }
        }
        LDS_FENCE();

        // ---- conv3 (32x32x16): pooled -> act3 V[4g][58] ----
#pragma unroll
        for (int t = 0; t < 2; ++t) {
            int n = t * 32 + n32;
            f32x16 acc = {0.f,0.f,0.f,0.f,0.f,0.f,0.f,0.f,0.f,0.f,0.f,0.f,0.f,0.f,0.f,0.f};
#pragma unroll
            for (int c = 0; c < 5; ++c) {
                h16x8 bfr = *(const h16x8*)&U[kg32 * 1056 + (n + c) * 8];
                acc = __builtin_amdgcn_mfma_f32_32x32x16_f16(a3[c], bfr, acc, 0, 0, 0);
            }
            if (n < 58) {
#pragma unroll
                for (int g = 0; g < 4; ++g) {
                    int r0 = 8 * g + 4 * kg32;
                    f32x4 bv = *(const f32x4*)&wsf[96 + r0];
                    uint2 p = pack4(lrelu(acc[4*g+0] + bv[0]), lrelu(acc[4*g+1] + bv[1]),
                                    lrelu(acc[4*g+2] + bv[2]), lrelu(acc[4*g+3] + bv[3]));
                    *(uint2*)&V[g * 552 + n * 8 + 4 * kg32] = p;
                }
            }
        }
        LDS_FENCE();

        // ---- conv4 (32x32x16): act3 -> act4 U[4g][54] ----
#pragma unroll
        for (int t = 0; t < 2; ++t) {
            int n = t * 32 + n32;
            f32x16 acc = {0.f,0.f,0.f,0.f,0.f,0.f,0.f,0.f,0.f,0.f,0.f,0.f,0.f,0.f,0.f,0.f};
#pragma unroll
            for (int c = 0; c < 10; ++c) {
                int k0 = c * 16 + kg32 * 8;
                int dk = k0 >> 5, g = (k0 >> 3) & 3;
                h16x8 bfr = *(const h16x8*)&V[g * 552 + (n + dk) * 8];
                acc = __builtin_amdgcn_mfma_f32_32x32x16_f16(a4[c], bfr, acc, 0, 0, 0);
            }
            if (n < 54) {
#pragma unroll
                for (int g = 0; g < 4; ++g) {
                    int r0 = 8 * g + 4 * kg32;
                    f32x4 bv = *(const f32x4*)&wsf[128 + r0];
                    uint2 p = pack4(lrelu(acc[4*g+0] + bv[0]), lrelu(acc[4*g+1] + bv[1]),
                                    lrelu(acc[4*g+2] + bv[2]), lrelu(acc[4*g+3] + bv[3]));
                    *(uint2*)&U[g * 448 + n * 8 + 4 * kg32] = p;
                }
            }
        }
        LDS_FENCE();

        // ---- pool2 + flatten: act4 -> flatb[slot], phys chunk = g*27 + pos ----
        if (lane < 27) {
#pragma unroll
            for (int g = 0; g < 4; ++g) {
                h16x8 pa = *(const h16x8*)&U[g * 448 + (2 * lane) * 8];
                h16x8 pb = *(const h16x8*)&U[g * 448 + (2 * lane + 1) * 8];
                h16x8 mm;
#pragma unroll
                for (int e = 0; e < 8; ++e) mm[e] = pa[e] > pb[e] ? pa[e] : pb[e];
                *(h16x8*)&flatb[slot][(g * 27 + lane) * 8] = mm;
            }
        }
    }
    __syncthreads();   // cross-wave: dense reads all 8 flatb slots

    // ---- dense (16x16x32): flatb[8][864] @ FD, wave w = m-tile ----
    int o0g = w * 16 + o16;
    f32x4 dacc = *(const f32x4*)&wsf[160 + o0g];  // bias in C
    for (int c = 0; c < 27; ++c) {
        h16x8 aw = *(const h16x8*)&FDg[((w * 27 + c) * 64 + lane) * 8];
        h16x8 bh = *(const h16x8*)&flatb[lane & 7][(kg16 * 27 + c) * 8];
        dacc = __builtin_amdgcn_mfma_f32_16x16x32_f16(aw, bh, dacc, 0, 0, 0);
    }
    f32x4 qov = *(const f32x4*)&wsf[224 + o0g];
    float part = 0.f;
#pragma unroll
    for (int q = 0; q < 4; ++q) part += lrelu(dacc[q]) * qov[q];
    red[tid] = part;
    __syncthreads();   // cross-wave: head reads all partials
    if (tid < 8) {
        float y = wsf[288];
#pragma unroll
        for (int g = 0; g < 16; ++g) y += red[(g >> 2) * 64 + (g & 3) * 16 + tid];
        if (f32flag) ((float*)out)[b0 + tid] = y;
        else         ((bf16*)out)[b0 + tid] = __float2bfloat16(y);
    }
}

extern "C" void kernel_launch(void* const* d_in, const int* in_sizes, int n_in,
                              void* d_out, int out_size, void* d_ws, size_t ws_size,
                              hipStream_t stream) {
    const void* x  = d_in[0];
    const void* w1 = d_in[1];
    const void* b1 = d_in[2];
    const void* w2 = d_in[3];
    const void* b2 = d_in[4];
    const void* w3 = d_in[5];
    const void* b3 = d_in[6];
    const void* w4 = d_in[7];
    const void* b4 = d_in[8];
    const void* wd = d_in[9];
    const void* bd = d_in[10];
    const void* wo = d_in[11];
    const void* bo = d_in[12];
    float* wsf = (float*)d_ws;

    int B = in_sizes[0] / 256;            // 32768
    prep<<<220, 256, 0, stream>>>((const unsigned short*)x,
                                  w1, w2, w3, w4, wd, wo,
                                  b1, b2, b3, b4, bd, bo, wsf);
    qcnn_main<<<B / 8, 256, 0, stream>>>(x, wsf, d_out);
}

// Round 12
// 191.884 us; speedup vs baseline: 1.0927x; 1.0147x over previous
//
#include <hip/hip_runtime.h>
#include <hip/hip_bf16.h>

typedef __hip_bfloat16 bf16;
typedef _Float16 h16;
typedef __attribute__((ext_vector_type(8))) _Float16 h16x8;
typedef __attribute__((ext_vector_type(4))) float f32x4;
typedef __attribute__((ext_vector_type(16))) float f32x16;

__device__ __forceinline__ float lrelu(float x) { return fmaxf(x, 0.1f * x); }
__device__ __forceinline__ float ldE(const void* p, long i, int f32) {
    return f32 ? ((const float*)p)[i] : __bfloat162float(((const bf16*)p)[i]);
}
__device__ __forceinline__ uint2 pack4(float a, float b, float c, float d) {
    union { _Float16 h[4]; uint2 u; } t;
    t.h[0] = (_Float16)a; t.h[1] = (_Float16)b; t.h[2] = (_Float16)c; t.h[3] = (_Float16)d;
    return t.u;
}
__device__ __forceinline__ unsigned umx(unsigned a, unsigned b) { return a > b ? a : b; }
// Compiler-only ordering barrier: wave-private buffers + in-order DS pipe
// (validated round 9).
#define LDS_FENCE() asm volatile("" ::: "memory")

// ---------------- workspace layout ----------------
// float region (wsf):
//   [64..79] fb1 [80..95] fb2 [96..127] fb3 [128..159] fb4
//   [160..223] fbd [224..287] qwo [288] fbo   int flag @ index 290
// f16 frag region wh = (h16*)(wsf+292):
//   F2 @0 (1024), F3 @1024 (2560), F4 @3584 (5120), FD @8704 (55296),
//   F1 @64000 (512)

__device__ __forceinline__ float qv(const void* src, int idx, float sc, int f32) {
    float w = ldE(src, idx, f32);
    float q = rintf(w / sc);                    // round-half-even like jnp.round
    return fminf(127.f, fmaxf(-127.f, q)) * sc; // clip then dequant
}

__device__ float block_scale(const void* src, int n, int f32, int tid, float* red) {
    unsigned m = 0;
    const uint4* p = (const uint4*)src;
    if (f32) {
        int nv = n >> 2;
        for (int i = tid; i < nv; i += 256) {
            uint4 u = p[i];
            m = umx(m, u.x & 0x7FFFFFFFu); m = umx(m, u.y & 0x7FFFFFFFu);
            m = umx(m, u.z & 0x7FFFFFFFu); m = umx(m, u.w & 0x7FFFFFFFu);
        }
        union { unsigned u; float f; } c; c.u = m;
        red[tid] = c.f;
    } else {
        int nv = n >> 3;
        for (int i = tid; i < nv; i += 256) {
            uint4 u = p[i];
            unsigned a;
            a = u.x & 0x7FFF7FFFu; m = umx(m, a >> 16); m = umx(m, a & 0xFFFFu);
            a = u.y & 0x7FFF7FFFu; m = umx(m, a >> 16); m = umx(m, a & 0xFFFFu);
            a = u.z & 0x7FFF7FFFu; m = umx(m, a >> 16); m = umx(m, a & 0xFFFFu);
            a = u.w & 0x7FFF7FFFu; m = umx(m, a >> 16); m = umx(m, a & 0xFFFFu);
        }
        union { unsigned u; float f; } c; c.u = m << 16;
        red[tid] = c.f;
    }
    __syncthreads();
    for (int s = 128; s > 0; s >>= 1) {
        if (tid < s) red[tid] = fmaxf(red[tid], red[tid + s]);
        __syncthreads();
    }
    float r = red[0] / 127.f;   // exact division, matches np max|w|/127
    __syncthreads();
    return r;
}

// Source-driven prep (r11): coalesced linear reads, inverse-mapped scatter
// stores. grid = 220: 0..215 FD, 216 F1+F2, 217 F3, 218 F4, 219 tail.
__global__ void __launch_bounds__(256) prep(
    const unsigned short* __restrict__ xu,
    const void* __restrict__ w1, const void* __restrict__ w2,
    const void* __restrict__ w3, const void* __restrict__ w4,
    const void* __restrict__ wd, const void* __restrict__ wo,
    const void* __restrict__ b1, const void* __restrict__ b2,
    const void* __restrict__ b3, const void* __restrict__ b4,
    const void* __restrict__ bd, const void* __restrict__ bo,
    float* __restrict__ wsf)
{
    int tid = threadIdx.x, which = blockIdx.x;
    __shared__ float red[256];
    __shared__ int cnt;
    if (tid == 0) cnt = 0;
    __syncthreads();
    int bad = 0;
    for (int i = tid; i < 2048; i += 256) {
        int e = (xu[i] >> 7) & 0xFF;      // bf16 exponent of x's halfwords
        if (e >= 147) bad = 1;            // |v| >= 2^20: x is not bf16 data
    }
    atomicAdd(&cnt, bad);
    __syncthreads();
    const int f32 = (cnt > 4) ? 1 : 0;
    h16* wh = (h16*)(wsf + 292);

    if (which < 216) {
        float sc = block_scale(wd, 55296, f32, tid, red);
        int s = which * 256 + tid;                 // 216*256 = 55296 exact
        int o = s / 864, r = s - o * 864;
        int cch = r / 27, i = r - cch * 27;
        int mt = o >> 4;
        int e = ((mt * 27 + i) * 64 + (o & 15) + (cch >> 3) * 16) * 8 + (cch & 7);
        wh[8704 + e] = (h16)qv(wd, s, sc, f32);
    } else if (which == 216) {
        float s1 = block_scale(w1, 64, f32, tid, red);
        float s2 = block_scale(w2, 768, f32, tid, red);
        for (int e = tid; e < 512; e += 256)  wh[64000 + e] = (h16)0.f;
        for (int e = tid; e < 1024; e += 256) wh[e] = (h16)0.f;
        __syncthreads();
        if (tid < 64) {    // w1[co][ci][dk]: s = co*4 + ci*2 + dk
            int s = tid, co = s >> 2, ci = (s >> 1) & 1, dk = s & 1;
            wh[64000 + (co + dk * 16) * 8 + ci] = (h16)qv(w1, s, s1, f32);
        }
        for (int s = tid; s < 768; s += 256) {  // w2: s = (mm*16+ci)*3 + dk
            int mm = s / 48, r = s - mm * 48;
            int ci = r / 3, dk = r - ci * 3;
            int k = dk * 16 + ci;
            int e = (k >> 5) * 512 + (mm + ((k >> 3) & 3) * 16) * 8 + (k & 7);
            wh[e] = (h16)qv(w2, s, s2, f32);
        }
    } else if (which == 217) {
        float sc = block_scale(w3, 2560, f32, tid, red);
        for (int s = tid; s < 2560; s += 256) {
            int mm = s / 80, r = s - mm * 80;
            int ci = r / 5, dk = r - ci * 5;
            int e = (dk * 64 + mm + (ci >> 3) * 32) * 8 + (ci & 7);
            wh[1024 + e] = (h16)qv(w3, s, sc, f32);
        }
    } else if (which == 218) {
        float sc = block_scale(w4, 5120, f32, tid, red);
        for (int s = tid; s < 5120; s += 256) {
            int mm = s / 160, r = s - mm * 160;
            int ci = r / 5, dk = r - ci * 5;
            int k = dk * 32 + ci;
            int e = (k >> 4) * 512 + (mm + ((k >> 3) & 1) * 32) * 8 + (k & 7);
            wh[3584 + e] = (h16)qv(w4, s, sc, f32);
        }
    } else {
        float sc = block_scale(wo, 64, f32, tid, red);
        if (tid < 64) wsf[224 + tid] = qv(wo, tid, sc, f32);
        if (tid < 16)        wsf[64 + tid]        = ldE(b1, tid, f32);
        else if (tid < 32)   wsf[80 + tid - 16]   = ldE(b2, tid - 16, f32);
        else if (tid < 64)   wsf[96 + tid - 32]   = ldE(b3, tid - 32, f32);
        else if (tid < 96)   wsf[128 + tid - 64]  = ldE(b4, tid - 64, f32);
        else if (tid < 160)  wsf[160 + tid - 96]  = ldE(bd, tid - 96, f32);
        else if (tid == 160) wsf[288]             = ldE(bo, 0, f32);
        if (tid == 0) ((int*)wsf)[290] = f32;
    }
}

// r9 structure + pool-interleaved act2/act4 physical rows (stride-1 pool
// reads, r10's validated conflict cut) + conv3/4 bias in MFMA C-init + x
// prefetch for both samples (it-loop fully unrolled -> static xl indexing,
// no scratch; VGPR cap 256 so no spill — WRITE_SIZE is the canary).
__global__ void __launch_bounds__(256, 2) qcnn_main(
    const void* __restrict__ x,      // [B][2][128] bf16 or f32
    const float* __restrict__ wsf,
    void* __restrict__ out)          // [B]
{
    const int f32flag = ((const int*)wsf)[290];
    const h16*  wh  = (const h16*)(wsf + 292);
    const h16*  F2g = wh;
    const h16*  F3g = wh + 1024;
    const h16*  F4g = wh + 3584;
    const h16*  FDg = wh + 8704;
    const h16*  F1g = wh + 64000;

    __shared__ __align__(16) h16 Uall[4][2112];   // act1 2gx132 / pooled / act4 4gx64
    __shared__ __align__(16) h16 Vall[4][2208];   // xi8 / act2 2gx126 / act3 4gx69
    __shared__ __align__(16) h16 flatb[8][872];
    __shared__ float red[256];

    int tid  = threadIdx.x;
    int lane = tid & 63;
    int w    = __builtin_amdgcn_readfirstlane(tid >> 6);
    int n16  = lane & 15, kg16 = (lane >> 4) & 3;
    int n32  = lane & 31, kg32 = (lane >> 5) & 1;
    int o16  = kg16 * 4;
    h16* U = Uall[w];
    h16* V = Vall[w];
    long b0 = (long)blockIdx.x * 8;

    h16x8 a1, a2[2], a3[5], a4[10];
    a1 = *(const h16x8*)&F1g[lane * 8];
#pragma unroll
    for (int c = 0; c < 2; ++c)  a2[c] = *(const h16x8*)&F2g[c * 512 + lane * 8];
#pragma unroll
    for (int c = 0; c < 5; ++c)  a3[c] = *(const h16x8*)&F3g[c * 512 + lane * 8];
#pragma unroll
    for (int c = 0; c < 10; ++c) a4[c] = *(const h16x8*)&F4g[c * 512 + lane * 8];
    f32x4 b1v = *(const f32x4*)&wsf[64 + o16];   // conv1 C-init
    f32x4 b2v = *(const f32x4*)&wsf[80 + o16];   // conv2 C-init
    f32x16 c3i, c4i;                             // conv3/4 C-init (bias rows)
#pragma unroll
    for (int g = 0; g < 4; ++g) {
        f32x4 bv3 = *(const f32x4*)&wsf[96 + 8 * g + 4 * kg32];
        f32x4 bv4 = *(const f32x4*)&wsf[128 + 8 * g + 4 * kg32];
#pragma unroll
        for (int q = 0; q < 4; ++q) { c3i[4*g+q] = bv3[q]; c4i[4*g+q] = bv4[q]; }
    }

    const h16 hz = (h16)0.f;
    const h16x8 zrow = {hz, hz, hz, hz, hz, hz, hz, hz};

    // prefetch both samples' x (global latency hidden behind it=0 compute)
    float xl[2][4];
#pragma unroll
    for (int it = 0; it < 2; ++it) {
        long sb = (b0 + w * 2 + it) * 256;
        xl[it][0] = ldE(x, sb + lane, f32flag);         // ch0, p = lane
        xl[it][1] = ldE(x, sb + 128 + lane, f32flag);   // ch1, p = lane
        xl[it][2] = ldE(x, sb + 64 + lane, f32flag);    // ch0, p = 64+lane
        xl[it][3] = ldE(x, sb + 192 + lane, f32flag);   // ch1, p = 64+lane
    }

#pragma unroll
    for (int it = 0; it < 2; ++it) {
        int slot = w * 2 + it;

        // ---- stage x as xi8 rows in V ----
        LDS_FENCE();
        {
            h16x8 r0 = zrow, r1 = zrow;
            r0[0] = (h16)xl[it][0]; r0[1] = (h16)xl[it][1];
            r1[0] = (h16)xl[it][2]; r1[1] = (h16)xl[it][3];
            *(h16x8*)&V[lane * 8]        = r0;
            *(h16x8*)&V[(64 + lane) * 8] = r1;
            if (lane < 3) *(h16x8*)&V[(128 + lane) * 8] = zrow;
        }
        LDS_FENCE();

        // ---- conv1 (16x16x32): xi8 -> act1 U[2g][127] ----
#pragma unroll
        for (int t = 0; t < 8; ++t) {
            int n = t * 16 + n16;
            f32x4 acc = b1v;
            h16x8 bfr = *(const h16x8*)&V[(n + kg16) * 8];
            acc = __builtin_amdgcn_mfma_f32_16x16x32_f16(a1, bfr, acc, 0, 0, 0);
            if (n < 127) {
                uint2 p = pack4(lrelu(acc[0]), lrelu(acc[1]), lrelu(acc[2]), lrelu(acc[3]));
                *(uint2*)&U[(o16 >> 3) * 1056 + n * 8 + (o16 & 7)] = p;
            }
        }
        if (lane < 8) {   // zero act1 pad rows 127..130 (act4 writes clobber them)
            int g = lane & 1, row = 127 + (lane >> 1);
            *(uint4*)&U[g * 1056 + row * 8] = make_uint4(0, 0, 0, 0);
        }
        LDS_FENCE();

        // ---- conv2: act1 -> act2 V[2g][126], POOL-INTERLEAVED:
        //      phys = (n&1)*64 + (n>>1)
#pragma unroll
        for (int t = 0; t < 8; ++t) {
            int n = t * 16 + n16;
            f32x4 acc = b2v;
#pragma unroll
            for (int c = 0; c < 2; ++c) {
                int k0 = c * 32 + kg16 * 8;
                int dk = k0 >> 4, g = (k0 & 15) >> 3;
                h16x8 bfr = *(const h16x8*)&U[g * 1056 + (n + dk) * 8];
                acc = __builtin_amdgcn_mfma_f32_16x16x32_f16(a2[c], bfr, acc, 0, 0, 0);
            }
            if (n < 125) {
                int ph = (n & 1) * 64 + (n >> 1);
                uint2 p = pack4(lrelu(acc[0]), lrelu(acc[1]), lrelu(acc[2]), lrelu(acc[3]));
                *(uint2*)&V[(o16 >> 3) * 1008 + ph * 8 + (o16 & 7)] = p;
            }
        }
        LDS_FENCE();

        // ---- pool1 (stride-1 reads): act2 -> pooled U[2g][62] ----
        if (lane < 62) {
#pragma unroll
            for (int g = 0; g < 2; ++g) {
                h16x8 pa = *(const h16x8*)&V[g * 1008 + lane * 8];         // even pos
                h16x8 pb = *(const h16x8*)&V[g * 1008 + (64 + lane) * 8];  // odd pos
                h16x8 mm;
#pragma unroll
                for (int e = 0; e < 8; ++e) mm[e] = pa[e] > pb[e] ? pa[e] : pb[e];
                *(h16x8*)&U[g * 1056 + lane * 8] = mm;
            }
        }
        LDS_FENCE();

        // ---- conv3 (32x32x16): pooled -> act3 V[4g][58] (bias in C) ----
#pragma unroll
        for (int t = 0; t < 2; ++t) {
            int n = t * 32 + n32;
            f32x16 acc = c3i;
#pragma unroll
            for (int c = 0; c < 5; ++c) {
                h16x8 bfr = *(const h16x8*)&U[kg32 * 1056 + (n + c) * 8];
                acc = __builtin_amdgcn_mfma_f32_32x32x16_f16(a3[c], bfr, acc, 0, 0, 0);
            }
            if (n < 58) {
#pragma unroll
                for (int g = 0; g < 4; ++g) {
                    uint2 p = pack4(lrelu(acc[4*g+0]), lrelu(acc[4*g+1]),
                                    lrelu(acc[4*g+2]), lrelu(acc[4*g+3]));
                    *(uint2*)&V[g * 552 + n * 8 + 4 * kg32] = p;
                }
            }
        }
        LDS_FENCE();

        // ---- conv4: act3 -> act4 U[4g][64], POOL-INTERLEAVED (bias in C):
        //      phys = (n&1)*32 + (n>>1)
#pragma unroll
        for (int t = 0; t < 2; ++t) {
            int n = t * 32 + n32;
            f32x16 acc = c4i;
#pragma unroll
            for (int c = 0; c < 10; ++c) {
                int k0 = c * 16 + kg32 * 8;
                int dk = k0 >> 5, g = (k0 >> 3) & 3;
                h16x8 bfr = *(const h16x8*)&V[g * 552 + (n + dk) * 8];
                acc = __builtin_amdgcn_mfma_f32_32x32x16_f16(a4[c], bfr, acc, 0, 0, 0);
            }
            if (n < 54) {
                int ph = (n & 1) * 32 + (n >> 1);
#pragma unroll
                for (int g = 0; g < 4; ++g) {
                    uint2 p = pack4(lrelu(acc[4*g+0]), lrelu(acc[4*g+1]),
                                    lrelu(acc[4*g+2]), lrelu(acc[4*g+3]));
                    *(uint2*)&U[g * 512 + ph * 8 + 4 * kg32] = p;
                }
            }
        }
        LDS_FENCE();

        // ---- pool2 (stride-1 reads) + flatten: act4 -> flatb[slot] ----
        if (lane < 27) {
#pragma unroll
            for (int g = 0; g < 4; ++g) {
                h16x8 pa = *(const h16x8*)&U[g * 512 + lane * 8];          // even pos
                h16x8 pb = *(const h16x8*)&U[g * 512 + (32 + lane) * 8];   // odd pos
                h16x8 mm;
#pragma unroll
                for (int e = 0; e < 8; ++e) mm[e] = pa[e] > pb[e] ? pa[e] : pb[e];
                *(h16x8*)&flatb[slot][(g * 27 + lane) * 8] = mm;
            }
        }
    }
    __syncthreads();   // cross-wave: dense reads all 8 flatb slots

    // ---- dense (16x16x32): flatb[8][864] @ FD, wave w = m-tile ----
    int o0g = w * 16 + o16;
    f32x4 dacc = *(const f32x4*)&wsf[160 + o0g];  // bias in C
    for (int c = 0; c < 27; ++c) {
        h16x8 aw = *(const h16x8*)&FDg[((w * 27 + c) * 64 + lane) * 8];
        h16x8 bh = *(const h16x8*)&flatb[lane & 7][(kg16 * 27 + c) * 8];
        dacc = __builtin_amdgcn_mfma_f32_16x16x32_f16(aw, bh, dacc, 0, 0, 0);
    }
    f32x4 qov = *(const f32x4*)&wsf[224 + o0g];
    float part = 0.f;
#pragma unroll
    for (int q = 0; q < 4; ++q) part += lrelu(dacc[q]) * qov[q];
    red[tid] = part;
    __syncthreads();   // cross-wave: head reads all partials
    if (tid < 8) {
        float y = wsf[288];
#pragma unroll
        for (int g = 0; g < 16; ++g) y += red[(g >> 2) * 64 + (g & 3) * 16 + tid];
        if (f32flag) ((float*)out)[b0 + tid] = y;
        else         ((bf16*)out)[b0 + tid] = __float2bfloat16(y);
    }
}

extern "C" void kernel_launch(void* const* d_in, const int* in_sizes, int n_in,
                              void* d_out, int out_size, void* d_ws, size_t ws_size,
                              hipStream_t stream) {
    const void* x  = d_in[0];
    const void* w1 = d_in[1];
    const void* b1 = d_in[2];
    const void* w2 = d_in[3];
    const void* b2 = d_in[4];
    const void* w3 = d_in[5];
    const void* b3 = d_in[6];
    const void* w4 = d_in[7];
    const void* b4 = d_in[8];
    const void* wd = d_in[9];
    const void* bd = d_in[10];
    const void* wo = d_in[11];
    const void* bo = d_in[12];
    float* wsf = (float*)d_ws;

    int B = in_sizes[0] / 256;            // 32768
    prep<<<220, 256, 0, stream>>>((const unsigned short*)x,
                                  w1, w2, w3, w4, wd, wo,
                                  b1, b2, b3, b4, bd, bo, wsf);
    qcnn_main<<<B / 8, 256, 0, stream>>>(x, wsf, d_out);
}

// Round 14
// 179.136 us; speedup vs baseline: 1.1705x; 1.0712x over previous
//
#include <hip/hip_runtime.h>
#include <hip/hip_bf16.h>

typedef __hip_bfloat16 bf16;
typedef _Float16 h16;
typedef __attribute__((ext_vector_type(2))) _Float16 h16x2;
typedef __attribute__((ext_vector_type(2))) __fp16 fp16x2;
typedef __attribute__((ext_vector_type(8))) _Float16 h16x8;
typedef __attribute__((ext_vector_type(4))) float f32x4;
typedef __attribute__((ext_vector_type(16))) float f32x16;

__device__ __forceinline__ float lrelu(float x) { return fmaxf(x, 0.1f * x); }
__device__ __forceinline__ float ldE(const void* p, long i, int f32) {
    return f32 ? ((const float*)p)[i] : __bfloat162float(((const bf16*)p)[i]);
}
// Packed epilogue: f32x4 -> lrelu -> 4 h16 in a uint2.
// v_cvt_pkrtz_f16_f32 x2, then packed f16 lrelu (v_pk_mul/v_pk_max).
// (builtin returns __fp16x2; bitcast through union to _Float16x2)
__device__ __forceinline__ uint2 pk4l(float a, float b, float c, float d) {
    union { fp16x2 f; h16x2 h; } lo, hi;
    lo.f = __builtin_amdgcn_cvt_pkrtz(a, b);
    hi.f = __builtin_amdgcn_cvt_pkrtz(c, d);
    const h16x2 cl = {(h16)0.1f, (h16)0.1f};
    h16x2 lo2 = __builtin_elementwise_max(lo.h, lo.h * cl);
    h16x2 hi2 = __builtin_elementwise_max(hi.h, hi.h * cl);
    union { h16x2 h[2]; uint2 u; } t;
    t.h[0] = lo2; t.h[1] = hi2;
    return t.u;
}
__device__ __forceinline__ unsigned umx(unsigned a, unsigned b) { return a > b ? a : b; }
// Compiler-only ordering barrier: wave-private buffers + in-order DS pipe
// (validated round 9).
#define LDS_FENCE() asm volatile("" ::: "memory")

// ---------------- workspace layout ----------------
// float region (wsf):
//   [64..79] fb1 [80..95] fb2 [96..127] fb3 [128..159] fb4
//   [160..223] fbd [224..287] qwo [288] fbo   int flag @ index 290
// f16 frag region wh = (h16*)(wsf+292):
//   F2 @0 (1024), F3 @1024 (2560), F4 @3584 (5120), FD @8704 (55296),
//   F1 @64000 (512)

__device__ __forceinline__ float qv(const void* src, int idx, float sc, int f32) {
    float w = ldE(src, idx, f32);
    float q = rintf(w / sc);                    // round-half-even like jnp.round
    return fminf(127.f, fmaxf(-127.f, q)) * sc; // clip then dequant
}

__device__ float block_scale(const void* src, int n, int f32, int tid, float* red) {
    unsigned m = 0;
    const uint4* p = (const uint4*)src;
    if (f32) {
        int nv = n >> 2;
        for (int i = tid; i < nv; i += 256) {
            uint4 u = p[i];
            m = umx(m, u.x & 0x7FFFFFFFu); m = umx(m, u.y & 0x7FFFFFFFu);
            m = umx(m, u.z & 0x7FFFFFFFu); m = umx(m, u.w & 0x7FFFFFFFu);
        }
        union { unsigned u; float f; } c; c.u = m;
        red[tid] = c.f;
    } else {
        int nv = n >> 3;
        for (int i = tid; i < nv; i += 256) {
            uint4 u = p[i];
            unsigned a;
            a = u.x & 0x7FFF7FFFu; m = umx(m, a >> 16); m = umx(m, a & 0xFFFFu);
            a = u.y & 0x7FFF7FFFu; m = umx(m, a >> 16); m = umx(m, a & 0xFFFFu);
            a = u.z & 0x7FFF7FFFu; m = umx(m, a >> 16); m = umx(m, a & 0xFFFFu);
            a = u.w & 0x7FFF7FFFu; m = umx(m, a >> 16); m = umx(m, a & 0xFFFFu);
        }
        union { unsigned u; float f; } c; c.u = m << 16;
        red[tid] = c.f;
    }
    __syncthreads();
    for (int s = 128; s > 0; s >>= 1) {
        if (tid < s) red[tid] = fmaxf(red[tid], red[tid + s]);
        __syncthreads();
    }
    float r = red[0] / 127.f;   // exact division, matches np max|w|/127
    __syncthreads();
    return r;
}

// Source-driven prep (r11): coalesced linear reads, inverse-mapped scatter
// stores. grid = 220: 0..215 FD, 216 F1+F2, 217 F3, 218 F4, 219 tail.
__global__ void __launch_bounds__(256) prep(
    const unsigned short* __restrict__ xu,
    const void* __restrict__ w1, const void* __restrict__ w2,
    const void* __restrict__ w3, const void* __restrict__ w4,
    const void* __restrict__ wd, const void* __restrict__ wo,
    const void* __restrict__ b1, const void* __restrict__ b2,
    const void* __restrict__ b3, const void* __restrict__ b4,
    const void* __restrict__ bd, const void* __restrict__ bo,
    float* __restrict__ wsf)
{
    int tid = threadIdx.x, which = blockIdx.x;
    __shared__ float red[256];
    __shared__ int cnt;
    if (tid == 0) cnt = 0;
    __syncthreads();
    int bad = 0;
    for (int i = tid; i < 2048; i += 256) {
        int e = (xu[i] >> 7) & 0xFF;      // bf16 exponent of x's halfwords
        if (e >= 147) bad = 1;            // |v| >= 2^20: x is not bf16 data
    }
    atomicAdd(&cnt, bad);
    __syncthreads();
    const int f32 = (cnt > 4) ? 1 : 0;
    h16* wh = (h16*)(wsf + 292);

    if (which < 216) {
        float sc = block_scale(wd, 55296, f32, tid, red);
        int s = which * 256 + tid;                 // 216*256 = 55296 exact
        int o = s / 864, r = s - o * 864;
        int cch = r / 27, i = r - cch * 27;
        int mt = o >> 4;
        int e = ((mt * 27 + i) * 64 + (o & 15) + (cch >> 3) * 16) * 8 + (cch & 7);
        wh[8704 + e] = (h16)qv(wd, s, sc, f32);
    } else if (which == 216) {
        float s1 = block_scale(w1, 64, f32, tid, red);
        float s2 = block_scale(w2, 768, f32, tid, red);
        for (int e = tid; e < 512; e += 256)  wh[64000 + e] = (h16)0.f;
        for (int e = tid; e < 1024; e += 256) wh[e] = (h16)0.f;
        __syncthreads();
        if (tid < 64) {    // w1[co][ci][dk]: s = co*4 + ci*2 + dk
            int s = tid, co = s >> 2, ci = (s >> 1) & 1, dk = s & 1;
            wh[64000 + (co + dk * 16) * 8 + ci] = (h16)qv(w1, s, s1, f32);
        }
        for (int s = tid; s < 768; s += 256) {  // w2: s = (mm*16+ci)*3 + dk
            int mm = s / 48, r = s - mm * 48;
            int ci = r / 3, dk = r - ci * 3;
            int k = dk * 16 + ci;
            int e = (k >> 5) * 512 + (mm + ((k >> 3) & 3) * 16) * 8 + (k & 7);
            wh[e] = (h16)qv(w2, s, s2, f32);
        }
    } else if (which == 217) {
        float sc = block_scale(w3, 2560, f32, tid, red);
        for (int s = tid; s < 2560; s += 256) {
            int mm = s / 80, r = s - mm * 80;
            int ci = r / 5, dk = r - ci * 5;
            int e = (dk * 64 + mm + (ci >> 3) * 32) * 8 + (ci & 7);
            wh[1024 + e] = (h16)qv(w3, s, sc, f32);
        }
    } else if (which == 218) {
        float sc = block_scale(w4, 5120, f32, tid, red);
        for (int s = tid; s < 5120; s += 256) {
            int mm = s / 160, r = s - mm * 160;
            int ci = r / 5, dk = r - ci * 5;
            int k = dk * 32 + ci;
            int e = (k >> 4) * 512 + (mm + ((k >> 3) & 1) * 32) * 8 + (k & 7);
            wh[3584 + e] = (h16)qv(w4, s, sc, f32);
        }
    } else {
        float sc = block_scale(wo, 64, f32, tid, red);
        if (tid < 64) wsf[224 + tid] = qv(wo, tid, sc, f32);
        if (tid < 16)        wsf[64 + tid]        = ldE(b1, tid, f32);
        else if (tid < 32)   wsf[80 + tid - 16]   = ldE(b2, tid - 16, f32);
        else if (tid < 64)   wsf[96 + tid - 32]   = ldE(b3, tid - 32, f32);
        else if (tid < 96)   wsf[128 + tid - 64]  = ldE(b4, tid - 64, f32);
        else if (tid < 160)  wsf[160 + tid - 96]  = ldE(bd, tid - 96, f32);
        else if (tid == 160) wsf[288]             = ldE(bo, 0, f32);
        if (tid == 0) ((int*)wsf)[290] = f32;
    }
}

// r12 structure (pool-interleaved act2/act4, bias-in-C, x prefetch) with
// packed-f16 epilogues: cvt_pkrtz + v_pk lrelu replaces f32 lrelu + scalar
// converts (~6 VALU vs ~14 per quad; 32 quads/sample).
__global__ void __launch_bounds__(256, 2) qcnn_main(
    const void* __restrict__ x,      // [B][2][128] bf16 or f32
    const float* __restrict__ wsf,
    void* __restrict__ out)          // [B]
{
    const int f32flag = ((const int*)wsf)[290];
    const h16*  wh  = (const h16*)(wsf + 292);
    const h16*  F2g = wh;
    const h16*  F3g = wh + 1024;
    const h16*  F4g = wh + 3584;
    const h16*  FDg = wh + 8704;
    const h16*  F1g = wh + 64000;

    __shared__ __align__(16) h16 Uall[4][2112];   // act1 2gx132 / pooled / act4 4gx64
    __shared__ __align__(16) h16 Vall[4][2208];   // xi8 / act2 2gx126 / act3 4gx69
    __shared__ __align__(16) h16 flatb[8][872];
    __shared__ float red[256];

    int tid  = threadIdx.x;
    int lane = tid & 63;
    int w    = __builtin_amdgcn_readfirstlane(tid >> 6);
    int n16  = lane & 15, kg16 = (lane >> 4) & 3;
    int n32  = lane & 31, kg32 = (lane >> 5) & 1;
    int o16  = kg16 * 4;
    h16* U = Uall[w];
    h16* V = Vall[w];
    long b0 = (long)blockIdx.x * 8;

    h16x8 a1, a2[2], a3[5], a4[10];
    a1 = *(const h16x8*)&F1g[lane * 8];
#pragma unroll
    for (int c = 0; c < 2; ++c)  a2[c] = *(const h16x8*)&F2g[c * 512 + lane * 8];
#pragma unroll
    for (int c = 0; c < 5; ++c)  a3[c] = *(const h16x8*)&F3g[c * 512 + lane * 8];
#pragma unroll
    for (int c = 0; c < 10; ++c) a4[c] = *(const h16x8*)&F4g[c * 512 + lane * 8];
    f32x4 b1v = *(const f32x4*)&wsf[64 + o16];   // conv1 C-init
    f32x4 b2v = *(const f32x4*)&wsf[80 + o16];   // conv2 C-init
    f32x16 c3i, c4i;                             // conv3/4 C-init (bias rows)
#pragma unroll
    for (int g = 0; g < 4; ++g) {
        f32x4 bv3 = *(const f32x4*)&wsf[96 + 8 * g + 4 * kg32];
        f32x4 bv4 = *(const f32x4*)&wsf[128 + 8 * g + 4 * kg32];
#pragma unroll
        for (int q = 0; q < 4; ++q) { c3i[4*g+q] = bv3[q]; c4i[4*g+q] = bv4[q]; }
    }

    const h16 hz = (h16)0.f;
    const h16x8 zrow = {hz, hz, hz, hz, hz, hz, hz, hz};

    // prefetch both samples' x (global latency hidden behind it=0 compute)
    float xl[2][4];
#pragma unroll
    for (int it = 0; it < 2; ++it) {
        long sb = (b0 + w * 2 + it) * 256;
        xl[it][0] = ldE(x, sb + lane, f32flag);         // ch0, p = lane
        xl[it][1] = ldE(x, sb + 128 + lane, f32flag);   // ch1, p = lane
        xl[it][2] = ldE(x, sb + 64 + lane, f32flag);    // ch0, p = 64+lane
        xl[it][3] = ldE(x, sb + 192 + lane, f32flag);   // ch1, p = 64+lane
    }

#pragma unroll
    for (int it = 0; it < 2; ++it) {
        int slot = w * 2 + it;

        // ---- stage x as xi8 rows in V ----
        LDS_FENCE();
        {
            h16x8 r0 = zrow, r1 = zrow;
            r0[0] = (h16)xl[it][0]; r0[1] = (h16)xl[it][1];
            r1[0] = (h16)xl[it][2]; r1[1] = (h16)xl[it][3];
            *(h16x8*)&V[lane * 8]        = r0;
            *(h16x8*)&V[(64 + lane) * 8] = r1;
            if (lane < 3) *(h16x8*)&V[(128 + lane) * 8] = zrow;
        }
        LDS_FENCE();

        // ---- conv1 (16x16x32): xi8 -> act1 U[2g][127] ----
#pragma unroll
        for (int t = 0; t < 8; ++t) {
            int n = t * 16 + n16;
            f32x4 acc = b1v;
            h16x8 bfr = *(const h16x8*)&V[(n + kg16) * 8];
            acc = __builtin_amdgcn_mfma_f32_16x16x32_f16(a1, bfr, acc, 0, 0, 0);
            if (n < 127) {
                *(uint2*)&U[(o16 >> 3) * 1056 + n * 8 + (o16 & 7)] =
                    pk4l(acc[0], acc[1], acc[2], acc[3]);
            }
        }
        if (lane < 8) {   // zero act1 pad rows 127..130
            int g = lane & 1, row = 127 + (lane >> 1);
            *(uint4*)&U[g * 1056 + row * 8] = make_uint4(0, 0, 0, 0);
        }
        LDS_FENCE();

        // ---- conv2: act1 -> act2 V[2g][126], POOL-INTERLEAVED:
        //      phys = (n&1)*64 + (n>>1)
#pragma unroll
        for (int t = 0; t < 8; ++t) {
            int n = t * 16 + n16;
            f32x4 acc = b2v;
#pragma unroll
            for (int c = 0; c < 2; ++c) {
                int k0 = c * 32 + kg16 * 8;
                int dk = k0 >> 4, g = (k0 & 15) >> 3;
                h16x8 bfr = *(const h16x8*)&U[g * 1056 + (n + dk) * 8];
                acc = __builtin_amdgcn_mfma_f32_16x16x32_f16(a2[c], bfr, acc, 0, 0, 0);
            }
            if (n < 125) {
                int ph = (n & 1) * 64 + (n >> 1);
                *(uint2*)&V[(o16 >> 3) * 1008 + ph * 8 + (o16 & 7)] =
                    pk4l(acc[0], acc[1], acc[2], acc[3]);
            }
        }
        LDS_FENCE();

        // ---- pool1 (stride-1 reads): act2 -> pooled U[2g][62] ----
        if (lane < 62) {
#pragma unroll
            for (int g = 0; g < 2; ++g) {
                h16x8 pa = *(const h16x8*)&V[g * 1008 + lane * 8];         // even pos
                h16x8 pb = *(const h16x8*)&V[g * 1008 + (64 + lane) * 8];  // odd pos
                h16x8 mm = __builtin_elementwise_max(pa, pb);
                *(h16x8*)&U[g * 1056 + lane * 8] = mm;
            }
        }
        LDS_FENCE();

        // ---- conv3 (32x32x16): pooled -> act3 V[4g][58] (bias in C) ----
#pragma unroll
        for (int t = 0; t < 2; ++t) {
            int n = t * 32 + n32;
            f32x16 acc = c3i;
#pragma unroll
            for (int c = 0; c < 5; ++c) {
                h16x8 bfr = *(const h16x8*)&U[kg32 * 1056 + (n + c) * 8];
                acc = __builtin_amdgcn_mfma_f32_32x32x16_f16(a3[c], bfr, acc, 0, 0, 0);
            }
            if (n < 58) {
#pragma unroll
                for (int g = 0; g < 4; ++g) {
                    *(uint2*)&V[g * 552 + n * 8 + 4 * kg32] =
                        pk4l(acc[4*g+0], acc[4*g+1], acc[4*g+2], acc[4*g+3]);
                }
            }
        }
        LDS_FENCE();

        // ---- conv4: act3 -> act4 U[4g][64], POOL-INTERLEAVED (bias in C):
        //      phys = (n&1)*32 + (n>>1)
#pragma unroll
        for (int t = 0; t < 2; ++t) {
            int n = t * 32 + n32;
            f32x16 acc = c4i;
#pragma unroll
            for (int c = 0; c < 10; ++c) {
                int k0 = c * 16 + kg32 * 8;
                int dk = k0 >> 5, g = (k0 >> 3) & 3;
                h16x8 bfr = *(const h16x8*)&V[g * 552 + (n + dk) * 8];
                acc = __builtin_amdgcn_mfma_f32_32x32x16_f16(a4[c], bfr, acc, 0, 0, 0);
            }
            if (n < 54) {
                int ph = (n & 1) * 32 + (n >> 1);
#pragma unroll
                for (int g = 0; g < 4; ++g) {
                    *(uint2*)&U[g * 512 + ph * 8 + 4 * kg32] =
                        pk4l(acc[4*g+0], acc[4*g+1], acc[4*g+2], acc[4*g+3]);
                }
            }
        }
        LDS_FENCE();

        // ---- pool2 (stride-1 reads) + flatten: act4 -> flatb[slot] ----
        if (lane < 27) {
#pragma unroll
            for (int g = 0; g < 4; ++g) {
                h16x8 pa = *(const h16x8*)&U[g * 512 + lane * 8];          // even pos
                h16x8 pb = *(const h16x8*)&U[g * 512 + (32 + lane) * 8];   // odd pos
                h16x8 mm = __builtin_elementwise_max(pa, pb);
                *(h16x8*)&flatb[slot][(g * 27 + lane) * 8] = mm;
            }
        }
    }
    __syncthreads();   // cross-wave: dense reads all 8 flatb slots

    // ---- dense (16x16x32): flatb[8][864] @ FD, wave w = m-tile ----
    int o0g = w * 16 + o16;
    f32x4 dacc = *(const f32x4*)&wsf[160 + o0g];  // bias in C
    for (int c = 0; c < 27; ++c) {
        h16x8 aw = *(const h16x8*)&FDg[((w * 27 + c) * 64 + lane) * 8];
        h16x8 bh = *(const h16x8*)&flatb[lane & 7][(kg16 * 27 + c) * 8];
        dacc = __builtin_amdgcn_mfma_f32_16x16x32_f16(aw, bh, dacc, 0, 0, 0);
    }
    f32x4 qov = *(const f32x4*)&wsf[224 + o0g];
    float part = 0.f;
#pragma unroll
    for (int q = 0; q < 4; ++q) part += lrelu(dacc[q]) * qov[q];
    red[tid] = part;
    __syncthreads();   // cross-wave: head reads all partials
    if (tid < 8) {
        float y = wsf[288];
#pragma unroll
        for (int g = 0; g < 16; ++g) y += red[(g >> 2) * 64 + (g & 3) * 16 + tid];
        if (f32flag) ((float*)out)[b0 + tid] = y;
        else         ((bf16*)out)[b0 + tid] = __float2bfloat16(y);
    }
}

extern "C" void kernel_launch(void* const* d_in, const int* in_sizes, int n_in,
                              void* d_out, int out_size, void* d_ws, size_t ws_size,
                              hipStream_t stream) {
    const void* x  = d_in[0];
    const void* w1 = d_in[1];
    const void* b1 = d_in[2];
    const void* w2 = d_in[3];
    const void* b2 = d_in[4];
    const void* w3 = d_in[5];
    const void* b3 = d_in[6];
    const void* w4 = d_in[7];
    const void* b4 = d_in[8];
    const void* wd = d_in[9];
    const void* bd = d_in[10];
    const void* wo = d_in[11];
    const void* bo = d_in[12];
    float* wsf = (float*)d_ws;

    int B = in_sizes[0] / 256;            // 32768
    prep<<<220, 256, 0, stream>>>((const unsigned short*)x,
                                  w1, w2, w3, w4, wd, wo,
                                  b1, b2, b3, b4, bd, bo, wsf);
    qcnn_main<<<B / 8, 256, 0, stream>>>(x, wsf, d_out);
}

// Round 15
// 177.587 us; speedup vs baseline: 1.1807x; 1.0087x over previous
//
#include <hip/hip_runtime.h>
#include <hip/hip_bf16.h>

typedef __hip_bfloat16 bf16;
typedef _Float16 h16;
typedef __attribute__((ext_vector_type(2))) _Float16 h16x2;
typedef __attribute__((ext_vector_type(2))) __fp16 fp16x2;
typedef __attribute__((ext_vector_type(8))) _Float16 h16x8;
typedef __attribute__((ext_vector_type(4))) float f32x4;
typedef __attribute__((ext_vector_type(16))) float f32x16;

__device__ __forceinline__ float lrelu(float x) { return fmaxf(x, 0.1f * x); }
__device__ __forceinline__ float ldE(const void* p, long i, int f32) {
    return f32 ? ((const float*)p)[i] : __bfloat162float(((const bf16*)p)[i]);
}
// Packed epilogue: f32x4 -> lrelu -> 4 h16 in a uint2 (cvt_pkrtz + v_pk ops).
__device__ __forceinline__ uint2 pk4l(float a, float b, float c, float d) {
    union { fp16x2 f; h16x2 h; } lo, hi;
    lo.f = __builtin_amdgcn_cvt_pkrtz(a, b);
    hi.f = __builtin_amdgcn_cvt_pkrtz(c, d);
    const h16x2 cl = {(h16)0.1f, (h16)0.1f};
    h16x2 lo2 = __builtin_elementwise_max(lo.h, lo.h * cl);
    h16x2 hi2 = __builtin_elementwise_max(hi.h, hi.h * cl);
    union { h16x2 h[2]; uint2 u; } t;
    t.h[0] = lo2; t.h[1] = hi2;
    return t.u;
}
// lane^1 swap on the VALU pipe (DPP quad_perm [1,0,3,2] = ctrl 0xB1) —
// NOT ds_swizzle/ds_bpermute (r8's shfl fusion hit the LDS pipe and lost).
__device__ __forceinline__ uint2 dpp_xor1(uint2 v) {
    uint2 r;
    r.x = (unsigned)__builtin_amdgcn_mov_dpp((int)v.x, 0xB1, 0xF, 0xF, true);
    r.y = (unsigned)__builtin_amdgcn_mov_dpp((int)v.y, 0xB1, 0xF, 0xF, true);
    return r;
}
// packed f16 max of two uint2-packed quads
__device__ __forceinline__ uint2 pkmax2(uint2 a, uint2 b) {
    union { unsigned u; h16x2 h; } ax, ay, bx, by, rx, ry;
    ax.u = a.x; ay.u = a.y; bx.u = b.x; by.u = b.y;
    rx.h = __builtin_elementwise_max(ax.h, bx.h);
    ry.h = __builtin_elementwise_max(ay.h, by.h);
    uint2 r; r.x = rx.u; r.y = ry.u;
    return r;
}
__device__ __forceinline__ unsigned umx(unsigned a, unsigned b) { return a > b ? a : b; }
// Compiler-only ordering barrier: wave-private buffers + in-order DS pipe
// (validated round 9).
#define LDS_FENCE() asm volatile("" ::: "memory")

// ---------------- workspace layout ----------------
// float region (wsf):
//   [64..79] fb1 [80..95] fb2 [96..127] fb3 [128..159] fb4
//   [160..223] fbd [224..287] qwo [288] fbo   int flag @ index 290
// f16 frag region wh = (h16*)(wsf+292):
//   F2 @0 (1024), F3 @1024 (2560), F4 @3584 (5120), FD @8704 (55296),
//   F1 @64000 (512)

__device__ __forceinline__ float qv(const void* src, int idx, float sc, int f32) {
    float w = ldE(src, idx, f32);
    float q = rintf(w / sc);                    // round-half-even like jnp.round
    return fminf(127.f, fmaxf(-127.f, q)) * sc; // clip then dequant
}

__device__ float block_scale(const void* src, int n, int f32, int tid, float* red) {
    unsigned m = 0;
    const uint4* p = (const uint4*)src;
    if (f32) {
        int nv = n >> 2;
        for (int i = tid; i < nv; i += 256) {
            uint4 u = p[i];
            m = umx(m, u.x & 0x7FFFFFFFu); m = umx(m, u.y & 0x7FFFFFFFu);
            m = umx(m, u.z & 0x7FFFFFFFu); m = umx(m, u.w & 0x7FFFFFFFu);
        }
        union { unsigned u; float f; } c; c.u = m;
        red[tid] = c.f;
    } else {
        int nv = n >> 3;
        for (int i = tid; i < nv; i += 256) {
            uint4 u = p[i];
            unsigned a;
            a = u.x & 0x7FFF7FFFu; m = umx(m, a >> 16); m = umx(m, a & 0xFFFFu);
            a = u.y & 0x7FFF7FFFu; m = umx(m, a >> 16); m = umx(m, a & 0xFFFFu);
            a = u.z & 0x7FFF7FFFu; m = umx(m, a >> 16); m = umx(m, a & 0xFFFFu);
            a = u.w & 0x7FFF7FFFu; m = umx(m, a >> 16); m = umx(m, a & 0xFFFFu);
        }
        union { unsigned u; float f; } c; c.u = m << 16;
        red[tid] = c.f;
    }
    __syncthreads();
    for (int s = 128; s > 0; s >>= 1) {
        if (tid < s) red[tid] = fmaxf(red[tid], red[tid + s]);
        __syncthreads();
    }
    float r = red[0] / 127.f;   // exact division, matches np max|w|/127
    __syncthreads();
    return r;
}

// Source-driven prep (r11): coalesced linear reads, inverse-mapped scatter
// stores. grid = 220: 0..215 FD, 216 F1+F2, 217 F3, 218 F4, 219 tail.
__global__ void __launch_bounds__(256) prep(
    const unsigned short* __restrict__ xu,
    const void* __restrict__ w1, const void* __restrict__ w2,
    const void* __restrict__ w3, const void* __restrict__ w4,
    const void* __restrict__ wd, const void* __restrict__ wo,
    const void* __restrict__ b1, const void* __restrict__ b2,
    const void* __restrict__ b3, const void* __restrict__ b4,
    const void* __restrict__ bd, const void* __restrict__ bo,
    float* __restrict__ wsf)
{
    int tid = threadIdx.x, which = blockIdx.x;
    __shared__ float red[256];
    __shared__ int cnt;
    if (tid == 0) cnt = 0;
    __syncthreads();
    int bad = 0;
    for (int i = tid; i < 2048; i += 256) {
        int e = (xu[i] >> 7) & 0xFF;      // bf16 exponent of x's halfwords
        if (e >= 147) bad = 1;            // |v| >= 2^20: x is not bf16 data
    }
    atomicAdd(&cnt, bad);
    __syncthreads();
    const int f32 = (cnt > 4) ? 1 : 0;
    h16* wh = (h16*)(wsf + 292);

    if (which < 216) {
        float sc = block_scale(wd, 55296, f32, tid, red);
        int s = which * 256 + tid;                 // 216*256 = 55296 exact
        int o = s / 864, r = s - o * 864;
        int cch = r / 27, i = r - cch * 27;
        int mt = o >> 4;
        int e = ((mt * 27 + i) * 64 + (o & 15) + (cch >> 3) * 16) * 8 + (cch & 7);
        wh[8704 + e] = (h16)qv(wd, s, sc, f32);
    } else if (which == 216) {
        float s1 = block_scale(w1, 64, f32, tid, red);
        float s2 = block_scale(w2, 768, f32, tid, red);
        for (int e = tid; e < 512; e += 256)  wh[64000 + e] = (h16)0.f;
        for (int e = tid; e < 1024; e += 256) wh[e] = (h16)0.f;
        __syncthreads();
        if (tid < 64) {    // w1[co][ci][dk]: s = co*4 + ci*2 + dk
            int s = tid, co = s >> 2, ci = (s >> 1) & 1, dk = s & 1;
            wh[64000 + (co + dk * 16) * 8 + ci] = (h16)qv(w1, s, s1, f32);
        }
        for (int s = tid; s < 768; s += 256) {  // w2: s = (mm*16+ci)*3 + dk
            int mm = s / 48, r = s - mm * 48;
            int ci = r / 3, dk = r - ci * 3;
            int k = dk * 16 + ci;
            int e = (k >> 5) * 512 + (mm + ((k >> 3) & 3) * 16) * 8 + (k & 7);
            wh[e] = (h16)qv(w2, s, s2, f32);
        }
    } else if (which == 217) {
        float sc = block_scale(w3, 2560, f32, tid, red);
        for (int s = tid; s < 2560; s += 256) {
            int mm = s / 80, r = s - mm * 80;
            int ci = r / 5, dk = r - ci * 5;
            int e = (dk * 64 + mm + (ci >> 3) * 32) * 8 + (ci & 7);
            wh[1024 + e] = (h16)qv(w3, s, sc, f32);
        }
    } else if (which == 218) {
        float sc = block_scale(w4, 5120, f32, tid, red);
        for (int s = tid; s < 5120; s += 256) {
            int mm = s / 160, r = s - mm * 160;
            int ci = r / 5, dk = r - ci * 5;
            int k = dk * 32 + ci;
            int e = (k >> 4) * 512 + (mm + ((k >> 3) & 1) * 32) * 8 + (k & 7);
            wh[3584 + e] = (h16)qv(w4, s, sc, f32);
        }
    } else {
        float sc = block_scale(wo, 64, f32, tid, red);
        if (tid < 64) wsf[224 + tid] = qv(wo, tid, sc, f32);
        if (tid < 16)        wsf[64 + tid]        = ldE(b1, tid, f32);
        else if (tid < 32)   wsf[80 + tid - 16]   = ldE(b2, tid - 16, f32);
        else if (tid < 64)   wsf[96 + tid - 32]   = ldE(b3, tid - 32, f32);
        else if (tid < 96)   wsf[128 + tid - 64]  = ldE(b4, tid - 64, f32);
        else if (tid < 160)  wsf[160 + tid - 96]  = ldE(bd, tid - 96, f32);
        else if (tid == 160) wsf[288]             = ldE(bo, 0, f32);
        if (tid == 0) ((int*)wsf)[290] = f32;
    }
}

// r14 structure with pools FUSED into conv2/conv4 epilogues via DPP lane^1
// swap (VALU pipe) + packed f16 max: pool1/pool2 stages deleted (-12 b128
// reads, -6 b128 writes, -2 fences per sample); act2/act4 never materialized.
// Safety: tile t's pooled writes (rows <= 8t+7) never alias later tiles'
// act1 reads (rows >= 16(t+1)); written pool pairs use only valid lanes.
__global__ void __launch_bounds__(256, 2) qcnn_main(
    const void* __restrict__ x,      // [B][2][128] bf16 or f32
    const float* __restrict__ wsf,
    void* __restrict__ out)          // [B]
{
    const int f32flag = ((const int*)wsf)[290];
    const h16*  wh  = (const h16*)(wsf + 292);
    const h16*  F2g = wh;
    const h16*  F3g = wh + 1024;
    const h16*  F4g = wh + 3584;
    const h16*  FDg = wh + 8704;
    const h16*  F1g = wh + 64000;

    __shared__ __align__(16) h16 Uall[4][2112];   // act1 2gx132 / pooled 2gx62
    __shared__ __align__(16) h16 Vall[4][2208];   // xi8 staging / act3 4gx69
    __shared__ __align__(16) h16 flatb[8][872];
    __shared__ float red[256];

    int tid  = threadIdx.x;
    int lane = tid & 63;
    int w    = __builtin_amdgcn_readfirstlane(tid >> 6);
    int n16  = lane & 15, kg16 = (lane >> 4) & 3;
    int n32  = lane & 31, kg32 = (lane >> 5) & 1;
    int o16  = kg16 * 4;
    h16* U = Uall[w];
    h16* V = Vall[w];
    long b0 = (long)blockIdx.x * 8;

    h16x8 a1, a2[2], a3[5], a4[10];
    a1 = *(const h16x8*)&F1g[lane * 8];
#pragma unroll
    for (int c = 0; c < 2; ++c)  a2[c] = *(const h16x8*)&F2g[c * 512 + lane * 8];
#pragma unroll
    for (int c = 0; c < 5; ++c)  a3[c] = *(const h16x8*)&F3g[c * 512 + lane * 8];
#pragma unroll
    for (int c = 0; c < 10; ++c) a4[c] = *(const h16x8*)&F4g[c * 512 + lane * 8];
    f32x4 b1v = *(const f32x4*)&wsf[64 + o16];   // conv1 C-init
    f32x4 b2v = *(const f32x4*)&wsf[80 + o16];   // conv2 C-init
    f32x16 c3i, c4i;                             // conv3/4 C-init (bias rows)
#pragma unroll
    for (int g = 0; g < 4; ++g) {
        f32x4 bv3 = *(const f32x4*)&wsf[96 + 8 * g + 4 * kg32];
        f32x4 bv4 = *(const f32x4*)&wsf[128 + 8 * g + 4 * kg32];
#pragma unroll
        for (int q = 0; q < 4; ++q) { c3i[4*g+q] = bv3[q]; c4i[4*g+q] = bv4[q]; }
    }

    const h16 hz = (h16)0.f;
    const h16x8 zrow = {hz, hz, hz, hz, hz, hz, hz, hz};

    // prefetch both samples' x (global latency hidden behind it=0 compute)
    float xl[2][4];
#pragma unroll
    for (int it = 0; it < 2; ++it) {
        long sb = (b0 + w * 2 + it) * 256;
        xl[it][0] = ldE(x, sb + lane, f32flag);         // ch0, p = lane
        xl[it][1] = ldE(x, sb + 128 + lane, f32flag);   // ch1, p = lane
        xl[it][2] = ldE(x, sb + 64 + lane, f32flag);    // ch0, p = 64+lane
        xl[it][3] = ldE(x, sb + 192 + lane, f32flag);   // ch1, p = 64+lane
    }

#pragma unroll
    for (int it = 0; it < 2; ++it) {
        int slot = w * 2 + it;

        // ---- stage x as xi8 rows in V (WAR vs prev conv4 reads: in-order DS) ----
        LDS_FENCE();
        {
            h16x8 r0 = zrow, r1 = zrow;
            r0[0] = (h16)xl[it][0]; r0[1] = (h16)xl[it][1];
            r1[0] = (h16)xl[it][2]; r1[1] = (h16)xl[it][3];
            *(h16x8*)&V[lane * 8]        = r0;
            *(h16x8*)&V[(64 + lane) * 8] = r1;
            if (lane < 3) *(h16x8*)&V[(128 + lane) * 8] = zrow;
        }
        LDS_FENCE();

        // ---- conv1 (16x16x32): xi8 -> act1 U[2g][127] ----
#pragma unroll
        for (int t = 0; t < 8; ++t) {
            int n = t * 16 + n16;
            f32x4 acc = b1v;
            h16x8 bfr = *(const h16x8*)&V[(n + kg16) * 8];
            acc = __builtin_amdgcn_mfma_f32_16x16x32_f16(a1, bfr, acc, 0, 0, 0);
            if (n < 127) {
                *(uint2*)&U[(o16 >> 3) * 1056 + n * 8 + (o16 & 7)] =
                    pk4l(acc[0], acc[1], acc[2], acc[3]);
            }
        }
        if (lane < 8) {   // zero act1 pad rows 127..130
            int g = lane & 1, row = 127 + (lane >> 1);
            *(uint4*)&U[g * 1056 + row * 8] = make_uint4(0, 0, 0, 0);
        }
        LDS_FENCE();

        // ---- conv2 + FUSED pool1: act1 -> pooled U[2g][62] directly.
        //      DPP lane^1 swap + packed max; even-n lanes write row n/2.
#pragma unroll
        for (int t = 0; t < 8; ++t) {
            int n = t * 16 + n16;
            f32x4 acc = b2v;
#pragma unroll
            for (int c = 0; c < 2; ++c) {
                int k0 = c * 32 + kg16 * 8;
                int dk = k0 >> 4, g = (k0 & 15) >> 3;
                h16x8 bfr = *(const h16x8*)&U[g * 1056 + (n + dk) * 8];
                acc = __builtin_amdgcn_mfma_f32_16x16x32_f16(a2[c], bfr, acc, 0, 0, 0);
            }
            uint2 p = pk4l(acc[0], acc[1], acc[2], acc[3]);   // all lanes (DPP src)
            uint2 m = pkmax2(p, dpp_xor1(p));
            if (!(n & 1) && n < 124) {   // pooled pairs (2i,2i+1), i<62
                *(uint2*)&U[(o16 >> 3) * 1056 + (n >> 1) * 8 + (o16 & 7)] = m;
            }
        }
        LDS_FENCE();

        // ---- conv3 (32x32x16): pooled -> act3 V[4g][58] (bias in C) ----
#pragma unroll
        for (int t = 0; t < 2; ++t) {
            int n = t * 32 + n32;
            f32x16 acc = c3i;
#pragma unroll
            for (int c = 0; c < 5; ++c) {
                h16x8 bfr = *(const h16x8*)&U[kg32 * 1056 + (n + c) * 8];
                acc = __builtin_amdgcn_mfma_f32_32x32x16_f16(a3[c], bfr, acc, 0, 0, 0);
            }
            if (n < 58) {
#pragma unroll
                for (int g = 0; g < 4; ++g) {
                    *(uint2*)&V[g * 552 + n * 8 + 4 * kg32] =
                        pk4l(acc[4*g+0], acc[4*g+1], acc[4*g+2], acc[4*g+3]);
                }
            }
        }
        LDS_FENCE();

        // ---- conv4 + FUSED pool2: act3 -> flatb[slot] directly.
        //      DPP lane^1 swap + packed max; even-n lanes write fp = n/2.
#pragma unroll
        for (int t = 0; t < 2; ++t) {
            int n = t * 32 + n32;
            f32x16 acc = c4i;
#pragma unroll
            for (int c = 0; c < 10; ++c) {
                int k0 = c * 16 + kg32 * 8;
                int dk = k0 >> 5, g = (k0 >> 3) & 3;
                h16x8 bfr = *(const h16x8*)&V[g * 552 + (n + dk) * 8];
                acc = __builtin_amdgcn_mfma_f32_32x32x16_f16(a4[c], bfr, acc, 0, 0, 0);
            }
#pragma unroll
            for (int g = 0; g < 4; ++g) {
                uint2 p = pk4l(acc[4*g+0], acc[4*g+1], acc[4*g+2], acc[4*g+3]);
                uint2 m = pkmax2(p, dpp_xor1(p));
                if (!(n & 1) && n < 54) {   // pairs (2i,2i+1), i<27
                    *(uint2*)&flatb[slot][(g * 27 + (n >> 1)) * 8 + 4 * kg32] = m;
                }
            }
        }
    }
    __syncthreads();   // cross-wave: dense reads all 8 flatb slots

    // ---- dense (16x16x32): flatb[8][864] @ FD, wave w = m-tile ----
    int o0g = w * 16 + o16;
    f32x4 dacc = *(const f32x4*)&wsf[160 + o0g];  // bias in C
    for (int c = 0; c < 27; ++c) {
        h16x8 aw = *(const h16x8*)&FDg[((w * 27 + c) * 64 + lane) * 8];
        h16x8 bh = *(const h16x8*)&flatb[lane & 7][(kg16 * 27 + c) * 8];
        dacc = __builtin_amdgcn_mfma_f32_16x16x32_f16(aw, bh, dacc, 0, 0, 0);
    }
    f32x4 qov = *(const f32x4*)&wsf[224 + o0g];
    float part = 0.f;
#pragma unroll
    for (int q = 0; q < 4; ++q) part += lrelu(dacc[q]) * qov[q];
    red[tid] = part;
    __syncthreads();   // cross-wave: head reads all partials
    if (tid < 8) {
        float y = wsf[288];
#pragma unroll
        for (int g = 0; g < 16; ++g) y += red[(g >> 2) * 64 + (g & 3) * 16 + tid];
        if (f32flag) ((float*)out)[b0 + tid] = y;
        else         ((bf16*)out)[b0 + tid] = __float2bfloat16(y);
    }
}

extern "C" void kernel_launch(void* const* d_in, const int* in_sizes, int n_in,
                              void* d_out, int out_size, void* d_ws, size_t ws_size,
                              hipStream_t stream) {
    const void* x  = d_in[0];
    const void* w1 = d_in[1];
    const void* b1 = d_in[2];
    const void* w2 = d_in[3];
    const void* b2 = d_in[4];
    const void* w3 = d_in[5];
    const void* b3 = d_in[6];
    const void* w4 = d_in[7];
    const void* b4 = d_in[8];
    const void* wd = d_in[9];
    const void* bd = d_in[10];
    const void* wo = d_in[11];
    const void* bo = d_in[12];
    float* wsf = (float*)d_ws;

    int B = in_sizes[0] / 256;            // 32768
    prep<<<220, 256, 0, stream>>>((const unsigned short*)x,
                                  w1, w2, w3, w4, wd, wo,
                                  b1, b2, b3, b4, bd, bo, wsf);
    qcnn_main<<<B / 8, 256, 0, stream>>>(x, wsf, d_out);
}